// Round 10
// baseline (169.938 us; speedup 1.0000x reference)
//
#include <hip/hip_runtime.h>
#include <math.h>

#define Cch 128
#define Hh 128
#define Ww 128
#define HW (Hh * Ww)

typedef __attribute__((ext_vector_type(8))) short short8;
typedef __attribute__((ext_vector_type(4))) float float4v;
typedef __attribute__((ext_vector_type(2))) float float2v;
typedef __attribute__((ext_vector_type(4))) unsigned int uint4v;

__device__ __forceinline__ unsigned short f2bf(float f) {
    unsigned u = __float_as_uint(f);
    return (unsigned short)((u + 0x8000u) >> 16);
}
__device__ __forceinline__ float2v up2(unsigned u) {
    return (float2v){__uint_as_float(u << 16), __uint_as_float(u & 0xffff0000u)};
}
__device__ __forceinline__ unsigned packbf2(float lo, float hi) {
    unsigned a = __float_as_uint(lo), b = __float_as_uint(hi);
    return ((a + 0x8000u) >> 16) | ((b + 0x8000u) & 0xffff0000u);
}

// ---- K1 v3: x [B][C][H][W] fp32 -> xt [B][HW][C] bf16 (measured good) --------
__global__ __launch_bounds__(256) void pack_x_v3(const float* __restrict__ x,
                                                 unsigned short* __restrict__ xt) {
    __shared__ unsigned int tile[64][68];   // [px][c2], 17,408 B
    int t   = threadIdx.x;
    int blk = blockIdx.x;                  // 1024 = 4 images * 256 px-tiles
    int b   = blk >> 8;
    int p0  = (blk & 255) << 6;
    const float* xb = x + (size_t)b * Cch * HW + p0;

    int c2i = t >> 4;                      // 0..15 (channel-pair row)
    int q   = t & 15;                      // px quad
    #pragma unroll
    for (int it = 0; it < 4; ++it) {
        int c2 = it * 16 + c2i;
        int px = q * 4;
        float4v a = *(const float4v*)&xb[(size_t)(2 * c2) * HW + px];
        float4v c = *(const float4v*)&xb[(size_t)(2 * c2 + 1) * HW + px];
        #pragma unroll
        for (int j = 0; j < 4; ++j)
            tile[px + j][c2] = packbf2(a[j], c[j]);
    }
    __syncthreads();
    unsigned short* xtb = xt + (size_t)b * HW * Cch + (size_t)p0 * Cch;
    int g  = t & 15;                       // channel octet
    int pw = t >> 4;                       // 0..15
    #pragma unroll
    for (int it = 0; it < 4; ++it) {
        int p = pw + 16 * it;
        uint4v v = *(const uint4v*)&tile[p][g * 4];
        *(uint4v*)(xtb + (size_t)p * Cch + g * 8) = v;
    }
}

// ---- K2: build B-fragment-linear weight layouts (bf16) -----------------------
#define NFB (9 * 4 * 8 * 64 * 8)
#define NFO (9 * 4 * 2 * 64 * 8)
__global__ __launch_bounds__(256) void build_frags(const float* __restrict__ w_def,
                                                   const float* __restrict__ w_off,
                                                   unsigned short* __restrict__ wfB,
                                                   unsigned short* __restrict__ wfO) {
    int idx = blockIdx.x * 256 + threadIdx.x;
    if (idx < NFB) {
        int j = idx & 7, lane = (idx >> 3) & 63, t = (idx >> 9) & 7;
        int q = (idx >> 12) & 3, k = idx >> 14;
        int c = 32 * q + 8 * (lane >> 4) + j;
        int o = 16 * t + (lane & 15);
        wfB[idx] = f2bf(w_def[(size_t)(o * Cch + c) * 9 + k]);
    } else if (idx < NFB + NFO) {
        int i2 = idx - NFB;
        int j = i2 & 7, lane = (i2 >> 3) & 63, t = (i2 >> 9) & 1;
        int q = (i2 >> 10) & 3, k = i2 >> 12;
        int c = 32 * q + 8 * (lane >> 4) + j;
        int o = 16 * t + (lane & 15);
        wfO[i2] = (o < 18) ? f2bf(w_off[(size_t)(o * Cch + c) * 9 + k]) : (unsigned short)0;
    }
}

// ---- block -> (b, h, w0): XCD-pinned (blk%8 = XCD, 2 XCDs per image) ---------
__device__ __forceinline__ void blk_map(int blk, int& b, int& h, int& w0) {
    int xcd = blk & 7;
    b = xcd >> 1;
    int seg = ((xcd & 1) << 8) | (blk >> 3);  // 0..511
    h  = seg >> 2;
    w0 = (seg & 3) << 5;
}

// ---- K3 v4: 4-wave role split (pt x chalf) -----------------------------------
// STRUCTURAL register fix: R9 anchor was 172 unified regs (u[2][8]=64 VGPR +
// acc[2][8]=64 AGPR) -> 2 waves/SIMD, latency-bound. Splitting pt across waves
// halves both: u[8]=32, acc[8]=32 AGPR. Estimated ~127 unified -> 3-4
// waves/SIMD. k-loop ORDER is byte-identical to the anchor schedule (R3/R7/R8:
// any reorder at low occupancy regresses). Per-wave smw permute stays private
// (wave region = 128 uint4v), same perm mapping per (pt,chalf).
__global__ __launch_bounds__(256, 2) void fused_srt4(const unsigned short* __restrict__ xt,
                                                     const unsigned short* __restrict__ wfB,
                                                     const unsigned short* __restrict__ wfO,
                                                     const float* __restrict__ b_off,
                                                     const float* __restrict__ b_def,
                                                     const float* __restrict__ w_attn,
                                                     const float* __restrict__ b_attn,
                                                     float* __restrict__ out) {
    __shared__ float4v red[2 * 8 * 64];   // 16 KiB (phase1 uses first 256)
    __shared__ float   offs[32 * 18];     // 2.3 KiB
    __shared__ uint4v  smw[4 * 2 * 64];   // 8 KiB: per-wave private permute
    int b, h, w0;
    blk_map(blockIdx.x, b, h, w0);
    int tid   = threadIdx.x;
    int wave  = tid >> 6;
    int lane  = tid & 63;
    int pt    = wave & 1;          // pixel-half this wave owns (0:px0-15, 1:px16-31)
    int chalf = wave >> 1;         // input-channel half (0:c0-63, 1:c64-127)
    int col   = lane & 15;
    int s     = lane >> 4;
    int spx   = lane >> 2;         // sorted: pixel index 0..15 within pt-half
    int sch   = lane & 3;          // sorted: 16-B chunk within 64-B row segment
    int csrt  = 64 * chalf + sch * 8;                    // ushort offset
    int wbase = wave * 128;                              // smw base (uint4v)
    int rIdx  = wbase + ((lane & 15) * 4 + (lane >> 4)); // frag-gather source

    const unsigned short* xtb = xt + (size_t)b * HW * Cch;

    // ================= Phase 1: offset conv ===================================
    {
        float4v acc2[2];
        #pragma unroll
        for (int t = 0; t < 2; ++t) {
            int o = 16 * t + col;
            float bv = (chalf == 0 && o < 18) ? b_off[o] : 0.0f;
            acc2[t] = (float4v){bv, bv, bv, bv};
        }

        #pragma unroll
        for (int k = 0; k < 9; ++k) {
            int y = h + (k / 3) - 1;
            bool vy = (y >= 0) && (y < Hh);
            int yc = min(max(y, 0), Hh - 1);
            int dxk = (k % 3) - 1;
            int px = w0 + 16 * pt + spx;
            int xs = px + dxk;
            bool val = vy && (xs >= 0) && (xs < Ww);
            int xc = min(max(xs, 0), Ww - 1);
            int ofs = (yc * Ww + xc) * Cch + csrt;
            #pragma unroll
            for (int qq = 0; qq < 2; ++qq) {
                uint4v av = *(const uint4v*)(xtb + ofs + 32 * qq);
                if (!val) av = (uint4v){0u, 0u, 0u, 0u};
                smw[wbase + qq * 64 + lane] = av;
            }
            short8 aa[2];
            #pragma unroll
            for (int qq = 0; qq < 2; ++qq)
                aa[qq] = __builtin_bit_cast(short8, smw[rIdx + qq * 64]);
            #pragma unroll
            for (int qq = 0; qq < 2; ++qq) {
                int q = 2 * chalf + qq;
                #pragma unroll
                for (int t = 0; t < 2; ++t) {
                    short8 bv = *(const short8*)(wfO + ((size_t)((k * 4 + q) * 2 + t) * 64 + lane) * 8);
                    acc2[t] = __builtin_amdgcn_mfma_f32_16x16x32_bf16(aa[qq], bv, acc2[t], 0, 0, 0);
                }
            }
        }
        if (chalf == 1) {
            #pragma unroll
            for (int t = 0; t < 2; ++t)
                red[(pt * 2 + t) * 64 + lane] = acc2[t];
        }
        __syncthreads();
        if (chalf == 0) {
            #pragma unroll
            for (int t = 0; t < 2; ++t) {
                float4v v = acc2[t] + red[(pt * 2 + t) * 64 + lane];
                int o = 16 * t + col;
                if (o < 18) {
                    #pragma unroll
                    for (int r = 0; r < 4; ++r)
                        offs[(16 * pt + 4 * s + r) * 18 + o] = v[r];
                }
            }
        }
        __syncthreads();
    }

    // ================= Phase 2: sorted gather pipeline + permute + MFMA =======
    float4v acc[8];
    #pragma unroll
    for (int t = 0; t < 8; ++t) {
        float bv = (chalf == 0) ? b_def[16 * t + col] : 0.0f;
        acc[t] = (float4v){bv, bv, bv, bv};
    }

    int    oaddr[4];   // [corner]
    float  wxy[4];     // a0,a1,b0,b1
    uint4v u[8];       // [qq*4 + corner]

#define CALC_TAP(K_) do {                                                    \
    int ky = ((K_) * 11) >> 5;                                               \
    int kx = (K_) - 3 * ky;                                                  \
    int pxl = 16 * pt + spx;                                                 \
    int px  = w0 + pxl;                                                      \
    float2 dv = *(const float2*)&offs[pxl * 18 + 2 * (K_)];                  \
    float ys = (float)(h - 1 + ky) + dv.x;                                   \
    float xs = (float)(px - 1 + kx) + dv.y;                                  \
    float y0f = floorf(ys), x0f = floorf(xs);                                \
    float wy = ys - y0f, wx = xs - x0f;                                      \
    int y0 = (int)y0f, x0 = (int)x0f;                                        \
    bool vy0 = (y0 >= 0) && (y0 < Hh);                                       \
    bool vy1 = (y0 + 1 >= 0) && (y0 + 1 < Hh);                               \
    bool vx0 = (x0 >= 0) && (x0 < Ww);                                       \
    bool vx1 = (x0 + 1 >= 0) && (x0 + 1 < Ww);                               \
    int y0c = min(max(y0, 0), Hh - 1), y1c = min(max(y0 + 1, 0), Hh - 1);    \
    int x0c = min(max(x0, 0), Ww - 1), x1c = min(max(x0 + 1, 0), Ww - 1);    \
    wxy[0] = vx0 ? (1.0f - wx) : 0.0f;                                       \
    wxy[1] = vx1 ? wx : 0.0f;                                                \
    wxy[2] = vy0 ? (1.0f - wy) : 0.0f;                                       \
    wxy[3] = vy1 ? wy : 0.0f;                                                \
    oaddr[0] = (y0c * Ww + x0c) * Cch + csrt;                                \
    oaddr[1] = (y0c * Ww + x1c) * Cch + csrt;                                \
    oaddr[2] = (y1c * Ww + x0c) * Cch + csrt;                                \
    oaddr[3] = (y1c * Ww + x1c) * Cch + csrt;                                \
} while (0)

#define LOAD_TAP() do {                                                      \
    _Pragma("unroll")                                                        \
    for (int qq = 0; qq < 2; ++qq)                                           \
        _Pragma("unroll")                                                    \
        for (int c4 = 0; c4 < 4; ++c4)                                       \
            u[qq * 4 + c4] = *(const uint4v*)(xtb + oaddr[c4] + 32 * qq);    \
} while (0)

    CALC_TAP(0);
    LOAD_TAP();

    #pragma unroll
    for (int k = 0; k < 9; ++k) {
        // 1. weight prefetch (both halves at top -- anchor schedule)
        const unsigned short* wk = wfB + (size_t)k * 16384 + (size_t)(2 * chalf) * 4096;
        short8 bva[8], bvb[8];
        #pragma unroll
        for (int t = 0; t < 8; ++t) {
            bva[t] = *(const short8*)(wk + (size_t)t * 512 + (size_t)lane * 8);
            bvb[t] = *(const short8*)(wk + 4096 + (size_t)t * 512 + (size_t)lane * 8);
        }
        // 2. blend (sorted layout, lane-local) + permute-write
        {
            float2v A0 = (float2v){wxy[0], wxy[0]};
            float2v A1 = (float2v){wxy[1], wxy[1]};
            float2v B0 = (float2v){wxy[2], wxy[2]};
            float2v B1 = (float2v){wxy[3], wxy[3]};
            #pragma unroll
            for (int qq = 0; qq < 2; ++qq) {
                uint4v res;
                #pragma unroll
                for (int j = 0; j < 4; ++j) {
                    float2v p00 = up2(u[qq * 4 + 0][j]);
                    float2v p01 = up2(u[qq * 4 + 1][j]);
                    float2v p10 = up2(u[qq * 4 + 2][j]);
                    float2v p11 = up2(u[qq * 4 + 3][j]);
                    float2v t0 = __builtin_elementwise_fma(A1, p01, A0 * p00);
                    float2v t1 = __builtin_elementwise_fma(A1, p11, A0 * p10);
                    float2v rr = __builtin_elementwise_fma(B1, t1, B0 * t0);
                    res[j] = packbf2(rr.x, rr.y);
                }
                smw[wbase + qq * 64 + lane] = res;
            }
        }
        // 3. next tap's addresses + gathers (reuse u)
        if (k < 8) {
            CALC_TAP(k + 1);
            LOAD_TAP();
        }
        // 4. permute-read into fragment layout, then MFMAs
        short8 afr[2];
        #pragma unroll
        for (int qq = 0; qq < 2; ++qq)
            afr[qq] = __builtin_bit_cast(short8, smw[rIdx + qq * 64]);
        #pragma unroll
        for (int t = 0; t < 8; ++t)
            acc[t] = __builtin_amdgcn_mfma_f32_16x16x32_bf16(afr[0], bva[t], acc[t], 0, 0, 0);
        #pragma unroll
        for (int t = 0; t < 8; ++t)
            acc[t] = __builtin_amdgcn_mfma_f32_16x16x32_bf16(afr[1], bvb[t], acc[t], 0, 0, 0);
    }
#undef CALC_TAP
#undef LOAD_TAP

    // ================= Phase 3: merge + attention epilogue =====================
    if (chalf == 1) {
        #pragma unroll
        for (int t = 0; t < 8; ++t)
            red[(pt * 8 + t) * 64 + lane] = acc[t];
    }
    __syncthreads();
    if (chalf == 0) {
        #pragma unroll
        for (int t = 0; t < 8; ++t)
            acc[t] += red[(pt * 8 + t) * 64 + lane];

        float wA[8];
        #pragma unroll
        for (int t = 0; t < 8; ++t) wA[t] = w_attn[16 * t + col];
        float battn = b_attn[0];
        float sig[4];
        #pragma unroll
        for (int r = 0; r < 4; ++r) {
            float pr = 0.0f;
            #pragma unroll
            for (int t = 0; t < 8; ++t) pr = fmaf(acc[t][r], wA[t], pr);
            #pragma unroll
            for (int m = 1; m < 16; m <<= 1) pr += __shfl_xor(pr, m, 64);
            sig[r] = 1.0f / (1.0f + expf(-(pr + battn)));
        }
        #pragma unroll
        for (int t = 0; t < 8; ++t) {
            int o = 16 * t + col;
            float4v v;
            #pragma unroll
            for (int r = 0; r < 4; ++r)
                v[r] = fmaxf(acc[t][r] * sig[r], 0.0f);
            float* dst = out + ((size_t)(b * Cch + o)) * HW + h * Ww + w0 + 16 * pt + 4 * s;
            *(float4v*)dst = v;
        }
    }
}

// ---- launch ------------------------------------------------------------------
extern "C" void kernel_launch(void* const* d_in, const int* in_sizes, int n_in,
                              void* d_out, int out_size, void* d_ws, size_t ws_size,
                              hipStream_t stream) {
    const float* x      = (const float*)d_in[0];
    const float* w_off  = (const float*)d_in[1];
    const float* b_off  = (const float*)d_in[2];
    const float* w_def  = (const float*)d_in[3];
    const float* b_def  = (const float*)d_in[4];
    const float* w_attn = (const float*)d_in[5];
    const float* b_attn = (const float*)d_in[6];
    float* out = (float*)d_out;

    char* ws = (char*)d_ws;
    unsigned short* xt  = (unsigned short*)ws;                       // 16,777,216 B
    unsigned short* wfB = (unsigned short*)(ws + 16777216);          //    294,912 B
    unsigned short* wfO = (unsigned short*)(ws + 17072128);          //     73,728 B

    pack_x_v3<<<1024, 256, 0, stream>>>(x, xt);
    build_frags<<<720, 256, 0, stream>>>(w_def, w_off, wfB, wfO);
    fused_srt4<<<2048, 256, 0, stream>>>(xt, wfB, wfO, b_off, b_def, w_attn, b_attn, out);
}

// Round 13
// 157.372 us; speedup vs baseline: 1.0799x; 1.0799x over previous
//
#include <hip/hip_runtime.h>
#include <math.h>

#define Cch 128
#define Hh 128
#define Ww 128
#define HW (Hh * Ww)

typedef __attribute__((ext_vector_type(8))) short short8;
typedef __attribute__((ext_vector_type(4))) float float4v;
typedef __attribute__((ext_vector_type(2))) float float2v;
typedef __attribute__((ext_vector_type(4))) unsigned int uint4v;

__device__ __forceinline__ unsigned short f2bf(float f) {
    unsigned u = __float_as_uint(f);
    return (unsigned short)((u + 0x8000u) >> 16);
}
__device__ __forceinline__ float2v up2(unsigned u) {
    return (float2v){__uint_as_float(u << 16), __uint_as_float(u & 0xffff0000u)};
}
__device__ __forceinline__ unsigned packbf2(float lo, float hi) {
    unsigned a = __float_as_uint(lo), b = __float_as_uint(hi);
    return ((a + 0x8000u) >> 16) | ((b + 0x8000u) & 0xffff0000u);
}

// ---- K1 v3: x [B][C][H][W] fp32 -> xt [B][HW][C] bf16 (measured good) --------
__global__ __launch_bounds__(256) void pack_x_v3(const float* __restrict__ x,
                                                 unsigned short* __restrict__ xt) {
    __shared__ unsigned int tile[64][68];   // [px][c2], 17,408 B
    int t   = threadIdx.x;
    int blk = blockIdx.x;                  // 1024 = 4 images * 256 px-tiles
    int b   = blk >> 8;
    int p0  = (blk & 255) << 6;
    const float* xb = x + (size_t)b * Cch * HW + p0;

    int c2i = t >> 4;                      // 0..15 (channel-pair row)
    int q   = t & 15;                      // px quad
    #pragma unroll
    for (int it = 0; it < 4; ++it) {
        int c2 = it * 16 + c2i;
        int px = q * 4;
        float4v a = *(const float4v*)&xb[(size_t)(2 * c2) * HW + px];
        float4v c = *(const float4v*)&xb[(size_t)(2 * c2 + 1) * HW + px];
        #pragma unroll
        for (int j = 0; j < 4; ++j)
            tile[px + j][c2] = packbf2(a[j], c[j]);
    }
    __syncthreads();
    unsigned short* xtb = xt + (size_t)b * HW * Cch + (size_t)p0 * Cch;
    int g  = t & 15;                       // channel octet
    int pw = t >> 4;                       // 0..15
    #pragma unroll
    for (int it = 0; it < 4; ++it) {
        int p = pw + 16 * it;
        uint4v v = *(const uint4v*)&tile[p][g * 4];
        *(uint4v*)(xtb + (size_t)p * Cch + g * 8) = v;
    }
}

// ---- K2: build B-fragment-linear weight layouts (bf16) -----------------------
#define NFB (9 * 4 * 8 * 64 * 8)
#define NFO (9 * 4 * 2 * 64 * 8)
__global__ __launch_bounds__(256) void build_frags(const float* __restrict__ w_def,
                                                   const float* __restrict__ w_off,
                                                   unsigned short* __restrict__ wfB,
                                                   unsigned short* __restrict__ wfO) {
    int idx = blockIdx.x * 256 + threadIdx.x;
    if (idx < NFB) {
        int j = idx & 7, lane = (idx >> 3) & 63, t = (idx >> 9) & 7;
        int q = (idx >> 12) & 3, k = idx >> 14;
        int c = 32 * q + 8 * (lane >> 4) + j;
        int o = 16 * t + (lane & 15);
        wfB[idx] = f2bf(w_def[(size_t)(o * Cch + c) * 9 + k]);
    } else if (idx < NFB + NFO) {
        int i2 = idx - NFB;
        int j = i2 & 7, lane = (i2 >> 3) & 63, t = (i2 >> 9) & 1;
        int q = (i2 >> 10) & 3, k = i2 >> 12;
        int c = 32 * q + 8 * (lane >> 4) + j;
        int o = 16 * t + (lane & 15);
        wfO[i2] = (o < 18) ? f2bf(w_off[(size_t)(o * Cch + c) * 9 + k]) : (unsigned short)0;
    }
}

// ---- block -> (b, h, w0): XCD-pinned (blk%8 = XCD, 2 XCDs per image) ---------
__device__ __forceinline__ void blk_map(int blk, int& b, int& h, int& w0) {
    int xcd = blk & 7;
    b = xcd >> 1;
    int seg = ((xcd & 1) << 8) | (blk >> 3);  // 0..511
    h  = seg >> 2;
    w0 = (seg & 3) << 5;
}

// ---- K3 v5: R9 anchor + TWO-DEEP gather prefetch -----------------------------
// Session ledger: R3 forced-bound=spill; R7 setprio=+20VGPR; R8 reorder=stall;
// R10 4-wave split=-27% (ILP halved + weight dup; occupancy was NOT binding).
// => anchor is issue+latency bound at 2 waves/SIMD with ~44% stall cycles and
// 84 unused registers in the 2-wave budget (172/256 unified). Spend them on
// pipeline DEPTH: double-buffer u/wxy by tap parity; gathers for tap k are
// issued at iteration k-2 (~2 full iterations of cover vs ~1 MFMA group).
// k-loop body ORDER is byte-identical to the anchor. Est ~244/256 unified.
__global__ __launch_bounds__(128, 2) void fused_srt(const unsigned short* __restrict__ xt,
                                                    const unsigned short* __restrict__ wfB,
                                                    const unsigned short* __restrict__ wfO,
                                                    const float* __restrict__ b_off,
                                                    const float* __restrict__ b_def,
                                                    const float* __restrict__ w_attn,
                                                    const float* __restrict__ b_attn,
                                                    float* __restrict__ out) {
    __shared__ float4v red[2 * 8 * 64];   // 16 KiB
    __shared__ float   offs[32 * 18];     // 2.3 KiB
    __shared__ uint4v  smw[2 * 4 * 64];   // 8 KiB: per-wave sorted->frag permute
    int b, h, w0;
    blk_map(blockIdx.x, b, h, w0);
    int tid  = threadIdx.x;
    int wave = tid >> 6;
    int lane = tid & 63;
    int col  = lane & 15;
    int s    = lane >> 4;
    int spx  = lane >> 2;          // sorted: pixel index 0..15
    int sch  = lane & 3;           // sorted: 16-B chunk within 64-B row segment
    int cbase = 64 * wave;
    int csrt  = cbase + sch * 8;   // ushort offset of this lane's chunk
    int wbase = wave * 256;        // smw base (uint4v units)
    int rIdx  = wbase + ((lane & 15) * 4 + (lane >> 4));  // frag-gather source

    const unsigned short* xtb = xt + (size_t)b * HW * Cch;

    // ================= Phase 1: offset conv (unchanged anchor) ================
    {
        float4v acc2[2][2];
        #pragma unroll
        for (int pt = 0; pt < 2; ++pt)
            #pragma unroll
            for (int t = 0; t < 2; ++t) {
                int o = 16 * t + col;
                float bv = (wave == 0 && o < 18) ? b_off[o] : 0.0f;
                acc2[pt][t] = (float4v){bv, bv, bv, bv};
            }

        #pragma unroll
        for (int k = 0; k < 9; ++k) {
            int y = h + (k / 3) - 1;
            bool vy = (y >= 0) && (y < Hh);
            int yc = min(max(y, 0), Hh - 1);
            int dxk = (k % 3) - 1;
            int  ofs[2];
            bool val[2];
            #pragma unroll
            for (int pt = 0; pt < 2; ++pt) {
                int px = w0 + 16 * pt + spx;
                int xs = px + dxk;
                val[pt] = vy && (xs >= 0) && (xs < Ww);
                int xc  = min(max(xs, 0), Ww - 1);
                ofs[pt] = (yc * Ww + xc) * Cch + csrt;
            }
            #pragma unroll
            for (int pt = 0; pt < 2; ++pt)
                #pragma unroll
                for (int qq = 0; qq < 2; ++qq) {
                    uint4v av = *(const uint4v*)(xtb + ofs[pt] + 32 * qq);
                    if (!val[pt]) av = (uint4v){0u, 0u, 0u, 0u};
                    smw[wbase + (pt * 2 + qq) * 64 + lane] = av;
                }
            short8 aa[2][2];
            #pragma unroll
            for (int pt = 0; pt < 2; ++pt)
                #pragma unroll
                for (int qq = 0; qq < 2; ++qq)
                    aa[pt][qq] = __builtin_bit_cast(short8, smw[rIdx + (pt * 2 + qq) * 64]);
            #pragma unroll
            for (int qq = 0; qq < 2; ++qq) {
                int q = 2 * wave + qq;
                #pragma unroll
                for (int t = 0; t < 2; ++t) {
                    short8 bv = *(const short8*)(wfO + ((size_t)((k * 4 + q) * 2 + t) * 64 + lane) * 8);
                    #pragma unroll
                    for (int pt = 0; pt < 2; ++pt)
                        acc2[pt][t] = __builtin_amdgcn_mfma_f32_16x16x32_bf16(aa[pt][qq], bv, acc2[pt][t], 0, 0, 0);
                }
            }
        }
        if (wave == 1) {
            #pragma unroll
            for (int pt = 0; pt < 2; ++pt)
                #pragma unroll
                for (int t = 0; t < 2; ++t)
                    red[(pt * 2 + t) * 64 + lane] = acc2[pt][t];
        }
        __syncthreads();
        if (wave == 0) {
            #pragma unroll
            for (int pt = 0; pt < 2; ++pt)
                #pragma unroll
                for (int t = 0; t < 2; ++t) {
                    float4v v = acc2[pt][t] + red[(pt * 2 + t) * 64 + lane];
                    int o = 16 * t + col;
                    if (o < 18) {
                        #pragma unroll
                        for (int r = 0; r < 4; ++r)
                            offs[(16 * pt + 4 * s + r) * 18 + o] = v[r];
                    }
                }
        }
        __syncthreads();
    }

    // ================= Phase 2: two-deep gather pipeline + permute + MFMA =====
    float4v acc[2][8];
    #pragma unroll
    for (int pt = 0; pt < 2; ++pt)
        #pragma unroll
        for (int t = 0; t < 8; ++t) {
            float bv = (wave == 0) ? b_def[16 * t + col] : 0.0f;
            acc[pt][t] = (float4v){bv, bv, bv, bv};
        }

    int    oaddr[2][4];     // ephemeral per-prefetch
    float  wxy[2][2][4];    // [parity][pt][a0,a1,b0,b1]
    uint4v u[2][2][8];      // [parity][pt][qq*4 + corner]

// CALC_TAP(K_): fills wxy[(K_)&1] + oaddr.  LOAD_TAP(K_): oaddr -> u[(K_)&1].
// K_ is a compile-time literal in the fully-unrolled loop -> all indices static.
#define CALC_TAP(K_) do {                                                    \
    int ky = ((K_) * 11) >> 5;                                               \
    int kx = (K_) - 3 * ky;                                                  \
    _Pragma("unroll")                                                        \
    for (int pt = 0; pt < 2; ++pt) {                                         \
        int pxl = 16 * pt + spx;                                             \
        int px  = w0 + pxl;                                                  \
        float2 dv = *(const float2*)&offs[pxl * 18 + 2 * (K_)];              \
        float ys = (float)(h - 1 + ky) + dv.x;                               \
        float xs = (float)(px - 1 + kx) + dv.y;                              \
        float y0f = floorf(ys), x0f = floorf(xs);                            \
        float wy = ys - y0f, wx = xs - x0f;                                  \
        int y0 = (int)y0f, x0 = (int)x0f;                                    \
        bool vy0 = (y0 >= 0) && (y0 < Hh);                                   \
        bool vy1 = (y0 + 1 >= 0) && (y0 + 1 < Hh);                           \
        bool vx0 = (x0 >= 0) && (x0 < Ww);                                   \
        bool vx1 = (x0 + 1 >= 0) && (x0 + 1 < Ww);                           \
        int y0c = min(max(y0, 0), Hh - 1), y1c = min(max(y0 + 1, 0), Hh - 1);\
        int x0c = min(max(x0, 0), Ww - 1), x1c = min(max(x0 + 1, 0), Ww - 1);\
        wxy[(K_) & 1][pt][0] = vx0 ? (1.0f - wx) : 0.0f;                     \
        wxy[(K_) & 1][pt][1] = vx1 ? wx : 0.0f;                              \
        wxy[(K_) & 1][pt][2] = vy0 ? (1.0f - wy) : 0.0f;                     \
        wxy[(K_) & 1][pt][3] = vy1 ? wy : 0.0f;                              \
        oaddr[pt][0] = (y0c * Ww + x0c) * Cch + csrt;                        \
        oaddr[pt][1] = (y0c * Ww + x1c) * Cch + csrt;                        \
        oaddr[pt][2] = (y1c * Ww + x0c) * Cch + csrt;                        \
        oaddr[pt][3] = (y1c * Ww + x1c) * Cch + csrt;                        \
    }                                                                        \
} while (0)

#define LOAD_TAP(K_) do {                                                    \
    _Pragma("unroll")                                                        \
    for (int pt = 0; pt < 2; ++pt)                                           \
        _Pragma("unroll")                                                    \
        for (int qq = 0; qq < 2; ++qq)                                       \
            _Pragma("unroll")                                                \
            for (int c4 = 0; c4 < 4; ++c4)                                   \
                u[(K_) & 1][pt][qq * 4 + c4] =                               \
                    *(const uint4v*)(xtb + oaddr[pt][c4] + 32 * qq);         \
} while (0)

    // Prologue: fill both pipeline stages (32 gathers in flight).
    CALC_TAP(0);
    LOAD_TAP(0);
    CALC_TAP(1);
    LOAD_TAP(1);

    #pragma unroll
    for (int k = 0; k < 9; ++k) {
        // 1. weight prefetch (both halves at top -- anchor schedule)
        const unsigned short* wk = wfB + (size_t)k * 16384 + (size_t)(2 * wave) * 4096;
        short8 bva[8], bvb[8];
        #pragma unroll
        for (int t = 0; t < 8; ++t) {
            bva[t] = *(const short8*)(wk + (size_t)t * 512 + (size_t)lane * 8);
            bvb[t] = *(const short8*)(wk + 4096 + (size_t)t * 512 + (size_t)lane * 8);
        }
        // 2. blend from parity buffer k&1 (loaded two iterations ago)
        #pragma unroll
        for (int pt = 0; pt < 2; ++pt) {
            float2v A0 = (float2v){wxy[k & 1][pt][0], wxy[k & 1][pt][0]};
            float2v A1 = (float2v){wxy[k & 1][pt][1], wxy[k & 1][pt][1]};
            float2v B0 = (float2v){wxy[k & 1][pt][2], wxy[k & 1][pt][2]};
            float2v B1 = (float2v){wxy[k & 1][pt][3], wxy[k & 1][pt][3]};
            #pragma unroll
            for (int qq = 0; qq < 2; ++qq) {
                uint4v res;
                #pragma unroll
                for (int j = 0; j < 4; ++j) {
                    float2v p00 = up2(u[k & 1][pt][qq * 4 + 0][j]);
                    float2v p01 = up2(u[k & 1][pt][qq * 4 + 1][j]);
                    float2v p10 = up2(u[k & 1][pt][qq * 4 + 2][j]);
                    float2v p11 = up2(u[k & 1][pt][qq * 4 + 3][j]);
                    float2v t0 = __builtin_elementwise_fma(A1, p01, A0 * p00);
                    float2v t1 = __builtin_elementwise_fma(A1, p11, A0 * p10);
                    float2v rr = __builtin_elementwise_fma(B1, t1, B0 * t0);
                    res[j] = packbf2(rr.x, rr.y);
                }
                smw[wbase + (pt * 2 + qq) * 64 + lane] = res;
            }
        }
        // 3. prefetch tap k+2 into the parity slot just consumed ((k+2)&1==k&1)
        if (k < 7) {
            CALC_TAP(k + 2);
            LOAD_TAP(k + 2);
        }
        // 4. permute-read into fragment layout, then MFMAs (anchor order)
        short8 afr[2][2];
        #pragma unroll
        for (int pt = 0; pt < 2; ++pt)
            #pragma unroll
            for (int qq = 0; qq < 2; ++qq)
                afr[pt][qq] = __builtin_bit_cast(short8, smw[rIdx + (pt * 2 + qq) * 64]);
        #pragma unroll
        for (int t = 0; t < 8; ++t) {
            acc[0][t] = __builtin_amdgcn_mfma_f32_16x16x32_bf16(afr[0][0], bva[t], acc[0][t], 0, 0, 0);
            acc[1][t] = __builtin_amdgcn_mfma_f32_16x16x32_bf16(afr[1][0], bva[t], acc[1][t], 0, 0, 0);
        }
        #pragma unroll
        for (int t = 0; t < 8; ++t) {
            acc[0][t] = __builtin_amdgcn_mfma_f32_16x16x32_bf16(afr[0][1], bvb[t], acc[0][t], 0, 0, 0);
            acc[1][t] = __builtin_amdgcn_mfma_f32_16x16x32_bf16(afr[1][1], bvb[t], acc[1][t], 0, 0, 0);
        }
    }
#undef CALC_TAP
#undef LOAD_TAP

    // ================= Phase 3: merge + attention epilogue =====================
    if (wave == 1) {
        #pragma unroll
        for (int pt = 0; pt < 2; ++pt)
            #pragma unroll
            for (int t = 0; t < 8; ++t)
                red[(pt * 8 + t) * 64 + lane] = acc[pt][t];
    }
    __syncthreads();
    if (wave == 0) {
        #pragma unroll
        for (int pt = 0; pt < 2; ++pt)
            #pragma unroll
            for (int t = 0; t < 8; ++t)
                acc[pt][t] += red[(pt * 8 + t) * 64 + lane];

        float wA[8];
        #pragma unroll
        for (int t = 0; t < 8; ++t) wA[t] = w_attn[16 * t + col];
        float battn = b_attn[0];
        #pragma unroll
        for (int pt = 0; pt < 2; ++pt) {
            float sig[4];
            #pragma unroll
            for (int r = 0; r < 4; ++r) {
                float pr = 0.0f;
                #pragma unroll
                for (int t = 0; t < 8; ++t) pr = fmaf(acc[pt][t][r], wA[t], pr);
                #pragma unroll
                for (int m = 1; m < 16; m <<= 1) pr += __shfl_xor(pr, m, 64);
                sig[r] = 1.0f / (1.0f + expf(-(pr + battn)));
            }
            #pragma unroll
            for (int t = 0; t < 8; ++t) {
                int o = 16 * t + col;
                float4v v;
                #pragma unroll
                for (int r = 0; r < 4; ++r)
                    v[r] = fmaxf(acc[pt][t][r] * sig[r], 0.0f);
                float* dst = out + ((size_t)(b * Cch + o)) * HW + h * Ww + w0 + 16 * pt + 4 * s;
                *(float4v*)dst = v;
            }
        }
    }
}

// ---- launch ------------------------------------------------------------------
extern "C" void kernel_launch(void* const* d_in, const int* in_sizes, int n_in,
                              void* d_out, int out_size, void* d_ws, size_t ws_size,
                              hipStream_t stream) {
    const float* x      = (const float*)d_in[0];
    const float* w_off  = (const float*)d_in[1];
    const float* b_off  = (const float*)d_in[2];
    const float* w_def  = (const float*)d_in[3];
    const float* b_def  = (const float*)d_in[4];
    const float* w_attn = (const float*)d_in[5];
    const float* b_attn = (const float*)d_in[6];
    float* out = (float*)d_out;

    char* ws = (char*)d_ws;
    unsigned short* xt  = (unsigned short*)ws;                       // 16,777,216 B
    unsigned short* wfB = (unsigned short*)(ws + 16777216);          //    294,912 B
    unsigned short* wfO = (unsigned short*)(ws + 17072128);          //     73,728 B

    pack_x_v3<<<1024, 256, 0, stream>>>(x, xt);
    build_frags<<<720, 256, 0, stream>>>(w_def, w_off, wfB, wfO);
    fused_srt<<<2048, 128, 0, stream>>>(xt, wfB, wfO, b_off, b_def, w_attn, b_attn, out);
}

// Round 15
// 153.363 us; speedup vs baseline: 1.1081x; 1.0261x over previous
//
#include <hip/hip_runtime.h>
#include <math.h>

#define Cch 128
#define Hh 128
#define Ww 128
#define HW (Hh * Ww)

typedef __attribute__((ext_vector_type(8))) short short8;
typedef __attribute__((ext_vector_type(4))) float float4v;
typedef __attribute__((ext_vector_type(2))) float float2v;
typedef __attribute__((ext_vector_type(4))) unsigned int uint4v;

__device__ __forceinline__ unsigned short f2bf(float f) {
    unsigned u = __float_as_uint(f);
    return (unsigned short)((u + 0x8000u) >> 16);
}
__device__ __forceinline__ float2v up2(unsigned u) {
    return (float2v){__uint_as_float(u << 16), __uint_as_float(u & 0xffff0000u)};
}
__device__ __forceinline__ unsigned packbf2(float lo, float hi) {
    unsigned a = __float_as_uint(lo), b = __float_as_uint(hi);
    return ((a + 0x8000u) >> 16) | ((b + 0x8000u) & 0xffff0000u);
}

// ---- K1 v3: x [B][C][H][W] fp32 -> xt [B][HW][C] bf16 (measured good) --------
__global__ __launch_bounds__(256) void pack_x_v3(const float* __restrict__ x,
                                                 unsigned short* __restrict__ xt) {
    __shared__ unsigned int tile[64][68];   // [px][c2], 17,408 B
    int t   = threadIdx.x;
    int blk = blockIdx.x;                  // 1024 = 4 images * 256 px-tiles
    int b   = blk >> 8;
    int p0  = (blk & 255) << 6;
    const float* xb = x + (size_t)b * Cch * HW + p0;

    int c2i = t >> 4;                      // 0..15 (channel-pair row)
    int q   = t & 15;                      // px quad
    #pragma unroll
    for (int it = 0; it < 4; ++it) {
        int c2 = it * 16 + c2i;
        int px = q * 4;
        float4v a = *(const float4v*)&xb[(size_t)(2 * c2) * HW + px];
        float4v c = *(const float4v*)&xb[(size_t)(2 * c2 + 1) * HW + px];
        #pragma unroll
        for (int j = 0; j < 4; ++j)
            tile[px + j][c2] = packbf2(a[j], c[j]);
    }
    __syncthreads();
    unsigned short* xtb = xt + (size_t)b * HW * Cch + (size_t)p0 * Cch;
    int g  = t & 15;                       // channel octet
    int pw = t >> 4;                       // 0..15
    #pragma unroll
    for (int it = 0; it < 4; ++it) {
        int p = pw + 16 * it;
        uint4v v = *(const uint4v*)&tile[p][g * 4];
        *(uint4v*)(xtb + (size_t)p * Cch + g * 8) = v;
    }
}

// ---- K2: build B-fragment-linear weight layouts (bf16) -----------------------
#define NFB (9 * 4 * 8 * 64 * 8)
#define NFO (9 * 4 * 2 * 64 * 8)
__global__ __launch_bounds__(256) void build_frags(const float* __restrict__ w_def,
                                                   const float* __restrict__ w_off,
                                                   unsigned short* __restrict__ wfB,
                                                   unsigned short* __restrict__ wfO) {
    int idx = blockIdx.x * 256 + threadIdx.x;
    if (idx < NFB) {
        int j = idx & 7, lane = (idx >> 3) & 63, t = (idx >> 9) & 7;
        int q = (idx >> 12) & 3, k = idx >> 14;
        int c = 32 * q + 8 * (lane >> 4) + j;
        int o = 16 * t + (lane & 15);
        wfB[idx] = f2bf(w_def[(size_t)(o * Cch + c) * 9 + k]);
    } else if (idx < NFB + NFO) {
        int i2 = idx - NFB;
        int j = i2 & 7, lane = (i2 >> 3) & 63, t = (i2 >> 9) & 1;
        int q = (i2 >> 10) & 3, k = i2 >> 12;
        int c = 32 * q + 8 * (lane >> 4) + j;
        int o = 16 * t + (lane & 15);
        wfO[i2] = (o < 18) ? f2bf(w_off[(size_t)(o * Cch + c) * 9 + k]) : (unsigned short)0;
    }
}

// ---- block -> (b, h, w0): XCD-pinned (blk%8 = XCD, 2 XCDs per image) ---------
__device__ __forceinline__ void blk_map(int blk, int& b, int& h, int& w0) {
    int xcd = blk & 7;
    b = xcd >> 1;
    int seg = ((xcd & 1) << 8) | (blk >> 3);  // 0..511
    h  = seg >> 2;
    w0 = (seg & 3) << 5;
}

// ---- K3 v6: R9 anchor + loop-invariant offs HOIST ----------------------------
// Session ledger: R3 forced-bound=spill; R7 setprio=+20VGPR; R8 reorder=stall;
// R10 wave-split=-27%; R13 C-level dbuf prefetch = compiler sank loads (VGPR
// 112, perf == anchor). v6 is a SEMANTIC hoist the compiler cannot undo:
// offs[] is loop-invariant across the 9-tap loop but re-read from LDS every
// tap (~120cy lgkmcnt chain head before addr calc). Pre-load all 18 float2
// values into registers (dvr, +36 VGPR; 108+36 arch + 64 AGPR ~ 208 <= 256
// two-wave budget). k-loop body order otherwise byte-identical to the anchor
// (single u buffer, weights at top, LOAD after blend).
__global__ __launch_bounds__(128, 2) void fused_srt(const unsigned short* __restrict__ xt,
                                                    const unsigned short* __restrict__ wfB,
                                                    const unsigned short* __restrict__ wfO,
                                                    const float* __restrict__ b_off,
                                                    const float* __restrict__ b_def,
                                                    const float* __restrict__ w_attn,
                                                    const float* __restrict__ b_attn,
                                                    float* __restrict__ out) {
    __shared__ float4v red[2 * 8 * 64];   // 16 KiB
    __shared__ float   offs[32 * 18];     // 2.3 KiB
    __shared__ uint4v  smw[2 * 4 * 64];   // 8 KiB: per-wave sorted->frag permute
    int b, h, w0;
    blk_map(blockIdx.x, b, h, w0);
    int tid  = threadIdx.x;
    int wave = tid >> 6;
    int lane = tid & 63;
    int col  = lane & 15;
    int s    = lane >> 4;
    int spx  = lane >> 2;          // sorted: pixel index 0..15
    int sch  = lane & 3;           // sorted: 16-B chunk within 64-B row segment
    int cbase = 64 * wave;
    int csrt  = cbase + sch * 8;   // ushort offset of this lane's chunk
    int wbase = wave * 256;        // smw base (uint4v units)
    int rIdx  = wbase + ((lane & 15) * 4 + (lane >> 4));  // frag-gather source

    const unsigned short* xtb = xt + (size_t)b * HW * Cch;

    // ================= Phase 1: offset conv (unchanged anchor) ================
    {
        float4v acc2[2][2];
        #pragma unroll
        for (int pt = 0; pt < 2; ++pt)
            #pragma unroll
            for (int t = 0; t < 2; ++t) {
                int o = 16 * t + col;
                float bv = (wave == 0 && o < 18) ? b_off[o] : 0.0f;
                acc2[pt][t] = (float4v){bv, bv, bv, bv};
            }

        #pragma unroll
        for (int k = 0; k < 9; ++k) {
            int y = h + (k / 3) - 1;
            bool vy = (y >= 0) && (y < Hh);
            int yc = min(max(y, 0), Hh - 1);
            int dxk = (k % 3) - 1;
            int  ofs[2];
            bool val[2];
            #pragma unroll
            for (int pt = 0; pt < 2; ++pt) {
                int px = w0 + 16 * pt + spx;
                int xs = px + dxk;
                val[pt] = vy && (xs >= 0) && (xs < Ww);
                int xc  = min(max(xs, 0), Ww - 1);
                ofs[pt] = (yc * Ww + xc) * Cch + csrt;
            }
            #pragma unroll
            for (int pt = 0; pt < 2; ++pt)
                #pragma unroll
                for (int qq = 0; qq < 2; ++qq) {
                    uint4v av = *(const uint4v*)(xtb + ofs[pt] + 32 * qq);
                    if (!val[pt]) av = (uint4v){0u, 0u, 0u, 0u};
                    smw[wbase + (pt * 2 + qq) * 64 + lane] = av;
                }
            short8 aa[2][2];
            #pragma unroll
            for (int pt = 0; pt < 2; ++pt)
                #pragma unroll
                for (int qq = 0; qq < 2; ++qq)
                    aa[pt][qq] = __builtin_bit_cast(short8, smw[rIdx + (pt * 2 + qq) * 64]);
            #pragma unroll
            for (int qq = 0; qq < 2; ++qq) {
                int q = 2 * wave + qq;
                #pragma unroll
                for (int t = 0; t < 2; ++t) {
                    short8 bv = *(const short8*)(wfO + ((size_t)((k * 4 + q) * 2 + t) * 64 + lane) * 8);
                    #pragma unroll
                    for (int pt = 0; pt < 2; ++pt)
                        acc2[pt][t] = __builtin_amdgcn_mfma_f32_16x16x32_bf16(aa[pt][qq], bv, acc2[pt][t], 0, 0, 0);
                }
            }
        }
        if (wave == 1) {
            #pragma unroll
            for (int pt = 0; pt < 2; ++pt)
                #pragma unroll
                for (int t = 0; t < 2; ++t)
                    red[(pt * 2 + t) * 64 + lane] = acc2[pt][t];
        }
        __syncthreads();
        if (wave == 0) {
            #pragma unroll
            for (int pt = 0; pt < 2; ++pt)
                #pragma unroll
                for (int t = 0; t < 2; ++t) {
                    float4v v = acc2[pt][t] + red[(pt * 2 + t) * 64 + lane];
                    int o = 16 * t + col;
                    if (o < 18) {
                        #pragma unroll
                        for (int r = 0; r < 4; ++r)
                            offs[(16 * pt + 4 * s + r) * 18 + o] = v[r];
                    }
                }
        }
        __syncthreads();
    }

    // ================= Phase 2: sorted gather pipeline + permute + MFMA =======
    float4v acc[2][8];
    #pragma unroll
    for (int pt = 0; pt < 2; ++pt)
        #pragma unroll
        for (int t = 0; t < 8; ++t) {
            float bv = (wave == 0) ? b_def[16 * t + col] : 0.0f;
            acc[pt][t] = (float4v){bv, bv, bv, bv};
        }

    // v6 HOIST: offs is loop-invariant across the 9 taps -- pre-load this
    // lane's 2 pixels x 9 taps of (dy,dx) into registers. 18 ds_read_b64
    // batched here (pipelined) replaces 18 serial chain-head reads in-loop.
    float2 dvr[2][9];
    #pragma unroll
    for (int pt = 0; pt < 2; ++pt) {
        int pxl = 16 * pt + spx;
        #pragma unroll
        for (int K = 0; K < 9; ++K)
            dvr[pt][K] = *(const float2*)&offs[pxl * 18 + 2 * K];
    }

    int    oaddr[2][4];   // [pt][corner]
    float  wxy[2][4];     // [pt][a0,a1,b0,b1]
    uint4v u[2][8];       // [pt][qq*4 + corner]

#define CALC_TAP(K_) do {                                                    \
    int ky = ((K_) * 11) >> 5;                                               \
    int kx = (K_) - 3 * ky;                                                  \
    _Pragma("unroll")                                                        \
    for (int pt = 0; pt < 2; ++pt) {                                         \
        int pxl = 16 * pt + spx;                                             \
        int px  = w0 + pxl;                                                  \
        float2 dv = dvr[pt][(K_)];                                           \
        float ys = (float)(h - 1 + ky) + dv.x;                               \
        float xs = (float)(px - 1 + kx) + dv.y;                              \
        float y0f = floorf(ys), x0f = floorf(xs);                            \
        float wy = ys - y0f, wx = xs - x0f;                                  \
        int y0 = (int)y0f, x0 = (int)x0f;                                    \
        bool vy0 = (y0 >= 0) && (y0 < Hh);                                   \
        bool vy1 = (y0 + 1 >= 0) && (y0 + 1 < Hh);                           \
        bool vx0 = (x0 >= 0) && (x0 < Ww);                                   \
        bool vx1 = (x0 + 1 >= 0) && (x0 + 1 < Ww);                           \
        int y0c = min(max(y0, 0), Hh - 1), y1c = min(max(y0 + 1, 0), Hh - 1);\
        int x0c = min(max(x0, 0), Ww - 1), x1c = min(max(x0 + 1, 0), Ww - 1);\
        wxy[pt][0] = vx0 ? (1.0f - wx) : 0.0f;                               \
        wxy[pt][1] = vx1 ? wx : 0.0f;                                        \
        wxy[pt][2] = vy0 ? (1.0f - wy) : 0.0f;                               \
        wxy[pt][3] = vy1 ? wy : 0.0f;                                        \
        oaddr[pt][0] = (y0c * Ww + x0c) * Cch + csrt;                        \
        oaddr[pt][1] = (y0c * Ww + x1c) * Cch + csrt;                        \
        oaddr[pt][2] = (y1c * Ww + x0c) * Cch + csrt;                        \
        oaddr[pt][3] = (y1c * Ww + x1c) * Cch + csrt;                        \
    }                                                                        \
} while (0)

#define LOAD_TAP() do {                                                      \
    _Pragma("unroll")                                                        \
    for (int pt = 0; pt < 2; ++pt)                                           \
        _Pragma("unroll")                                                    \
        for (int qq = 0; qq < 2; ++qq)                                       \
            _Pragma("unroll")                                                \
            for (int c4 = 0; c4 < 4; ++c4)                                   \
                u[pt][qq * 4 + c4] =                                         \
                    *(const uint4v*)(xtb + oaddr[pt][c4] + 32 * qq);         \
} while (0)

    CALC_TAP(0);
    LOAD_TAP();

    #pragma unroll
    for (int k = 0; k < 9; ++k) {
        // 1. weight prefetch (both halves at top -- anchor schedule)
        const unsigned short* wk = wfB + (size_t)k * 16384 + (size_t)(2 * wave) * 4096;
        short8 bva[8], bvb[8];
        #pragma unroll
        for (int t = 0; t < 8; ++t) {
            bva[t] = *(const short8*)(wk + (size_t)t * 512 + (size_t)lane * 8);
            bvb[t] = *(const short8*)(wk + 4096 + (size_t)t * 512 + (size_t)lane * 8);
        }
        // 2. blend (sorted layout, lane-local) + permute-write
        #pragma unroll
        for (int pt = 0; pt < 2; ++pt) {
            float2v A0 = (float2v){wxy[pt][0], wxy[pt][0]};
            float2v A1 = (float2v){wxy[pt][1], wxy[pt][1]};
            float2v B0 = (float2v){wxy[pt][2], wxy[pt][2]};
            float2v B1 = (float2v){wxy[pt][3], wxy[pt][3]};
            #pragma unroll
            for (int qq = 0; qq < 2; ++qq) {
                uint4v res;
                #pragma unroll
                for (int j = 0; j < 4; ++j) {
                    float2v p00 = up2(u[pt][qq * 4 + 0][j]);
                    float2v p01 = up2(u[pt][qq * 4 + 1][j]);
                    float2v p10 = up2(u[pt][qq * 4 + 2][j]);
                    float2v p11 = up2(u[pt][qq * 4 + 3][j]);
                    float2v t0 = __builtin_elementwise_fma(A1, p01, A0 * p00);
                    float2v t1 = __builtin_elementwise_fma(A1, p11, A0 * p10);
                    float2v rr = __builtin_elementwise_fma(B1, t1, B0 * t0);
                    res[j] = packbf2(rr.x, rr.y);
                }
                smw[wbase + (pt * 2 + qq) * 64 + lane] = res;
            }
        }
        // 3. next tap's addresses + gathers (reuse u)
        if (k < 8) {
            CALC_TAP(k + 1);
            LOAD_TAP();
        }
        // 4. permute-read into fragment layout, then MFMAs (anchor order)
        short8 afr[2][2];
        #pragma unroll
        for (int pt = 0; pt < 2; ++pt)
            #pragma unroll
            for (int qq = 0; qq < 2; ++qq)
                afr[pt][qq] = __builtin_bit_cast(short8, smw[rIdx + (pt * 2 + qq) * 64]);
        #pragma unroll
        for (int t = 0; t < 8; ++t) {
            acc[0][t] = __builtin_amdgcn_mfma_f32_16x16x32_bf16(afr[0][0], bva[t], acc[0][t], 0, 0, 0);
            acc[1][t] = __builtin_amdgcn_mfma_f32_16x16x32_bf16(afr[1][0], bva[t], acc[1][t], 0, 0, 0);
        }
        #pragma unroll
        for (int t = 0; t < 8; ++t) {
            acc[0][t] = __builtin_amdgcn_mfma_f32_16x16x32_bf16(afr[0][1], bvb[t], acc[0][t], 0, 0, 0);
            acc[1][t] = __builtin_amdgcn_mfma_f32_16x16x32_bf16(afr[1][1], bvb[t], acc[1][t], 0, 0, 0);
        }
    }
#undef CALC_TAP
#undef LOAD_TAP

    // ================= Phase 3: merge + attention epilogue =====================
    if (wave == 1) {
        #pragma unroll
        for (int pt = 0; pt < 2; ++pt)
            #pragma unroll
            for (int t = 0; t < 8; ++t)
                red[(pt * 8 + t) * 64 + lane] = acc[pt][t];
    }
    __syncthreads();
    if (wave == 0) {
        #pragma unroll
        for (int pt = 0; pt < 2; ++pt)
            #pragma unroll
            for (int t = 0; t < 8; ++t)
                acc[pt][t] += red[(pt * 8 + t) * 64 + lane];

        float wA[8];
        #pragma unroll
        for (int t = 0; t < 8; ++t) wA[t] = w_attn[16 * t + col];
        float battn = b_attn[0];
        #pragma unroll
        for (int pt = 0; pt < 2; ++pt) {
            float sig[4];
            #pragma unroll
            for (int r = 0; r < 4; ++r) {
                float pr = 0.0f;
                #pragma unroll
                for (int t = 0; t < 8; ++t) pr = fmaf(acc[pt][t][r], wA[t], pr);
                #pragma unroll
                for (int m = 1; m < 16; m <<= 1) pr += __shfl_xor(pr, m, 64);
                sig[r] = 1.0f / (1.0f + expf(-(pr + battn)));
            }
            #pragma unroll
            for (int t = 0; t < 8; ++t) {
                int o = 16 * t + col;
                float4v v;
                #pragma unroll
                for (int r = 0; r < 4; ++r)
                    v[r] = fmaxf(acc[pt][t][r] * sig[r], 0.0f);
                float* dst = out + ((size_t)(b * Cch + o)) * HW + h * Ww + w0 + 16 * pt + 4 * s;
                *(float4v*)dst = v;
            }
        }
    }
}

// ---- launch ------------------------------------------------------------------
extern "C" void kernel_launch(void* const* d_in, const int* in_sizes, int n_in,
                              void* d_out, int out_size, void* d_ws, size_t ws_size,
                              hipStream_t stream) {
    const float* x      = (const float*)d_in[0];
    const float* w_off  = (const float*)d_in[1];
    const float* b_off  = (const float*)d_in[2];
    const float* w_def  = (const float*)d_in[3];
    const float* b_def  = (const float*)d_in[4];
    const float* w_attn = (const float*)d_in[5];
    const float* b_attn = (const float*)d_in[6];
    float* out = (float*)d_out;

    char* ws = (char*)d_ws;
    unsigned short* xt  = (unsigned short*)ws;                       // 16,777,216 B
    unsigned short* wfB = (unsigned short*)(ws + 16777216);          //    294,912 B
    unsigned short* wfO = (unsigned short*)(ws + 17072128);          //     73,728 B

    pack_x_v3<<<1024, 256, 0, stream>>>(x, xt);
    build_frags<<<720, 256, 0, stream>>>(w_def, w_off, wfB, wfO);
    fused_srt<<<2048, 128, 0, stream>>>(xt, wfB, wfO, b_off, b_def, w_attn, b_attn, out);
}

// Round 17
// 152.121 us; speedup vs baseline: 1.1171x; 1.0082x over previous
//
#include <hip/hip_runtime.h>
#include <math.h>

#define Cch 128
#define Hh 128
#define Ww 128
#define HW (Hh * Ww)

typedef __attribute__((ext_vector_type(8))) short short8;
typedef __attribute__((ext_vector_type(4))) float float4v;
typedef __attribute__((ext_vector_type(2))) float float2v;
typedef __attribute__((ext_vector_type(4))) unsigned int uint4v;

__device__ __forceinline__ unsigned short f2bf(float f) {
    unsigned u = __float_as_uint(f);
    return (unsigned short)((u + 0x8000u) >> 16);
}
__device__ __forceinline__ float2v up2(unsigned u) {
    return (float2v){__uint_as_float(u << 16), __uint_as_float(u & 0xffff0000u)};
}
__device__ __forceinline__ unsigned packbf2(float lo, float hi) {
    unsigned a = __float_as_uint(lo), b = __float_as_uint(hi);
    return ((a + 0x8000u) >> 16) | ((b + 0x8000u) & 0xffff0000u);
}

// ---- K1+K2 merged: blocks [0,1024) pack x -> xt bf16; [1024,1744) build
// weight fragments. The two jobs are fully independent -> merging deletes one
// launch boundary (inter-dispatch gaps measured ~10-25us under contention).
#define NFB (9 * 4 * 8 * 64 * 8)
#define NFO (9 * 4 * 2 * 64 * 8)
__global__ __launch_bounds__(256) void prep_all(const float* __restrict__ x,
                                                unsigned short* __restrict__ xt,
                                                const float* __restrict__ w_def,
                                                const float* __restrict__ w_off,
                                                unsigned short* __restrict__ wfB,
                                                unsigned short* __restrict__ wfO) {
    __shared__ unsigned int tile[64][68];   // [px][c2], 17,408 B (pack path only)
    int t   = threadIdx.x;
    int blk = blockIdx.x;
    if (blk < 1024) {
        // ---- pack_x_v3 body (measured good) ----
        int b   = blk >> 8;
        int p0  = (blk & 255) << 6;
        const float* xb = x + (size_t)b * Cch * HW + p0;
        int c2i = t >> 4;                  // 0..15 (channel-pair row)
        int q   = t & 15;                  // px quad
        #pragma unroll
        for (int it = 0; it < 4; ++it) {
            int c2 = it * 16 + c2i;
            int px = q * 4;
            float4v a = *(const float4v*)&xb[(size_t)(2 * c2) * HW + px];
            float4v c = *(const float4v*)&xb[(size_t)(2 * c2 + 1) * HW + px];
            #pragma unroll
            for (int j = 0; j < 4; ++j)
                tile[px + j][c2] = packbf2(a[j], c[j]);
        }
        __syncthreads();
        unsigned short* xtb = xt + (size_t)b * HW * Cch + (size_t)p0 * Cch;
        int g  = t & 15;                   // channel octet
        int pw = t >> 4;                   // 0..15
        #pragma unroll
        for (int it = 0; it < 4; ++it) {
            int p = pw + 16 * it;
            uint4v v = *(const uint4v*)&tile[p][g * 4];
            *(uint4v*)(xtb + (size_t)p * Cch + g * 8) = v;
        }
    } else {
        // ---- build_frags body (unchanged) ----
        int idx = (blk - 1024) * 256 + t;
        if (idx < NFB) {
            int j = idx & 7, lane = (idx >> 3) & 63, tt = (idx >> 9) & 7;
            int q = (idx >> 12) & 3, k = idx >> 14;
            int c = 32 * q + 8 * (lane >> 4) + j;
            int o = 16 * tt + (lane & 15);
            wfB[idx] = f2bf(w_def[(size_t)(o * Cch + c) * 9 + k]);
        } else if (idx < NFB + NFO) {
            int i2 = idx - NFB;
            int j = i2 & 7, lane = (i2 >> 3) & 63, tt = (i2 >> 9) & 1;
            int q = (i2 >> 10) & 3, k = i2 >> 12;
            int c = 32 * q + 8 * (lane >> 4) + j;
            int o = 16 * tt + (lane & 15);
            wfO[i2] = (o < 18) ? f2bf(w_off[(size_t)(o * Cch + c) * 9 + k]) : (unsigned short)0;
        }
    }
}

// ---- block -> (b, h, w0): XCD-pinned (blk%8 = XCD, 2 XCDs per image) ---------
__device__ __forceinline__ void blk_map(int blk, int& b, int& h, int& w0) {
    int xcd = blk & 7;
    b = xcd >> 1;
    int seg = ((xcd & 1) << 8) | (blk >> 3);  // 0..511
    h  = seg >> 2;
    w0 = (seg & 3) << 5;
}

// ---- K3: ANCHOR config (R9-measured ~70us, byte-exact) -----------------------
// Session ledger (all measured): R3 forced-bound=spill -17%; R7 setprio=+20
// VGPR -18%; R8 reorder=stall -70%; R10 wave-split=-27%; R13 C-level dbuf =
// compiler sank loads (==); R15 value hoist = compiler re-sank (==, VGPR 108).
// => latency-bound fixed point of this decomposition; only escape is an
// all-asm VMEM loop (negative expected value at current bench reliability).
__global__ __launch_bounds__(128, 2) void fused_srt(const unsigned short* __restrict__ xt,
                                                    const unsigned short* __restrict__ wfB,
                                                    const unsigned short* __restrict__ wfO,
                                                    const float* __restrict__ b_off,
                                                    const float* __restrict__ b_def,
                                                    const float* __restrict__ w_attn,
                                                    const float* __restrict__ b_attn,
                                                    float* __restrict__ out) {
    __shared__ float4v red[2 * 8 * 64];   // 16 KiB
    __shared__ float   offs[32 * 18];     // 2.3 KiB
    __shared__ uint4v  smw[2 * 4 * 64];   // 8 KiB: per-wave sorted->frag permute
    int b, h, w0;
    blk_map(blockIdx.x, b, h, w0);
    int tid  = threadIdx.x;
    int wave = tid >> 6;
    int lane = tid & 63;
    int col  = lane & 15;
    int s    = lane >> 4;
    int spx  = lane >> 2;          // sorted: pixel index 0..15
    int sch  = lane & 3;           // sorted: 16-B chunk within 64-B row segment
    int cbase = 64 * wave;
    int csrt  = cbase + sch * 8;   // ushort offset of this lane's chunk
    int wbase = wave * 256;        // smw base (uint4v units)
    int rIdx  = wbase + ((lane & 15) * 4 + (lane >> 4));  // frag-gather source

    const unsigned short* xtb = xt + (size_t)b * HW * Cch;

    // ================= Phase 1: offset conv (sorted loads + permute) ==========
    {
        float4v acc2[2][2];
        #pragma unroll
        for (int pt = 0; pt < 2; ++pt)
            #pragma unroll
            for (int t = 0; t < 2; ++t) {
                int o = 16 * t + col;
                float bv = (wave == 0 && o < 18) ? b_off[o] : 0.0f;
                acc2[pt][t] = (float4v){bv, bv, bv, bv};
            }

        #pragma unroll
        for (int k = 0; k < 9; ++k) {
            int y = h + (k / 3) - 1;
            bool vy = (y >= 0) && (y < Hh);
            int yc = min(max(y, 0), Hh - 1);
            int dxk = (k % 3) - 1;
            int  ofs[2];
            bool val[2];
            #pragma unroll
            for (int pt = 0; pt < 2; ++pt) {
                int px = w0 + 16 * pt + spx;
                int xs = px + dxk;
                val[pt] = vy && (xs >= 0) && (xs < Ww);
                int xc  = min(max(xs, 0), Ww - 1);
                ofs[pt] = (yc * Ww + xc) * Cch + csrt;
            }
            #pragma unroll
            for (int pt = 0; pt < 2; ++pt)
                #pragma unroll
                for (int qq = 0; qq < 2; ++qq) {
                    uint4v av = *(const uint4v*)(xtb + ofs[pt] + 32 * qq);
                    if (!val[pt]) av = (uint4v){0u, 0u, 0u, 0u};
                    smw[wbase + (pt * 2 + qq) * 64 + lane] = av;
                }
            short8 aa[2][2];
            #pragma unroll
            for (int pt = 0; pt < 2; ++pt)
                #pragma unroll
                for (int qq = 0; qq < 2; ++qq)
                    aa[pt][qq] = __builtin_bit_cast(short8, smw[rIdx + (pt * 2 + qq) * 64]);
            #pragma unroll
            for (int qq = 0; qq < 2; ++qq) {
                int q = 2 * wave + qq;
                #pragma unroll
                for (int t = 0; t < 2; ++t) {
                    short8 bv = *(const short8*)(wfO + ((size_t)((k * 4 + q) * 2 + t) * 64 + lane) * 8);
                    #pragma unroll
                    for (int pt = 0; pt < 2; ++pt)
                        acc2[pt][t] = __builtin_amdgcn_mfma_f32_16x16x32_bf16(aa[pt][qq], bv, acc2[pt][t], 0, 0, 0);
                }
            }
        }
        if (wave == 1) {
            #pragma unroll
            for (int pt = 0; pt < 2; ++pt)
                #pragma unroll
                for (int t = 0; t < 2; ++t)
                    red[(pt * 2 + t) * 64 + lane] = acc2[pt][t];
        }
        __syncthreads();
        if (wave == 0) {
            #pragma unroll
            for (int pt = 0; pt < 2; ++pt)
                #pragma unroll
                for (int t = 0; t < 2; ++t) {
                    float4v v = acc2[pt][t] + red[(pt * 2 + t) * 64 + lane];
                    int o = 16 * t + col;
                    if (o < 18) {
                        #pragma unroll
                        for (int r = 0; r < 4; ++r)
                            offs[(16 * pt + 4 * s + r) * 18 + o] = v[r];
                    }
                }
        }
        __syncthreads();
    }

    // ================= Phase 2: sorted gather pipeline + permute + MFMA =======
    float4v acc[2][8];
    #pragma unroll
    for (int pt = 0; pt < 2; ++pt)
        #pragma unroll
        for (int t = 0; t < 8; ++t) {
            float bv = (wave == 0) ? b_def[16 * t + col] : 0.0f;
            acc[pt][t] = (float4v){bv, bv, bv, bv};
        }

    int    oaddr[2][4];   // [pt][corner]
    float  wxy[2][4];     // [pt][a0,a1,b0,b1]
    uint4v u[2][8];       // [pt][qq*4 + corner]

#define CALC_TAP(K_) do {                                                    \
    int ky = ((K_) * 11) >> 5;                                               \
    int kx = (K_) - 3 * ky;                                                  \
    _Pragma("unroll")                                                        \
    for (int pt = 0; pt < 2; ++pt) {                                         \
        int pxl = 16 * pt + spx;                                             \
        int px  = w0 + pxl;                                                  \
        float2 dv = *(const float2*)&offs[pxl * 18 + 2 * (K_)];              \
        float ys = (float)(h - 1 + ky) + dv.x;                               \
        float xs = (float)(px - 1 + kx) + dv.y;                              \
        float y0f = floorf(ys), x0f = floorf(xs);                            \
        float wy = ys - y0f, wx = xs - x0f;                                  \
        int y0 = (int)y0f, x0 = (int)x0f;                                    \
        bool vy0 = (y0 >= 0) && (y0 < Hh);                                   \
        bool vy1 = (y0 + 1 >= 0) && (y0 + 1 < Hh);                           \
        bool vx0 = (x0 >= 0) && (x0 < Ww);                                   \
        bool vx1 = (x0 + 1 >= 0) && (x0 + 1 < Ww);                           \
        int y0c = min(max(y0, 0), Hh - 1), y1c = min(max(y0 + 1, 0), Hh - 1);\
        int x0c = min(max(x0, 0), Ww - 1), x1c = min(max(x0 + 1, 0), Ww - 1);\
        wxy[pt][0] = vx0 ? (1.0f - wx) : 0.0f;                               \
        wxy[pt][1] = vx1 ? wx : 0.0f;                                        \
        wxy[pt][2] = vy0 ? (1.0f - wy) : 0.0f;                               \
        wxy[pt][3] = vy1 ? wy : 0.0f;                                        \
        oaddr[pt][0] = (y0c * Ww + x0c) * Cch + csrt;                        \
        oaddr[pt][1] = (y0c * Ww + x1c) * Cch + csrt;                        \
        oaddr[pt][2] = (y1c * Ww + x0c) * Cch + csrt;                        \
        oaddr[pt][3] = (y1c * Ww + x1c) * Cch + csrt;                        \
    }                                                                        \
} while (0)

#define LOAD_TAP() do {                                                      \
    _Pragma("unroll")                                                        \
    for (int pt = 0; pt < 2; ++pt)                                           \
        _Pragma("unroll")                                                    \
        for (int qq = 0; qq < 2; ++qq)                                       \
            _Pragma("unroll")                                                \
            for (int c4 = 0; c4 < 4; ++c4)                                   \
                u[pt][qq * 4 + c4] =                                         \
                    *(const uint4v*)(xtb + oaddr[pt][c4] + 32 * qq);         \
} while (0)

    CALC_TAP(0);
    LOAD_TAP();

    #pragma unroll
    for (int k = 0; k < 9; ++k) {
        // 1. weight prefetch (both halves at top -- measured-good schedule)
        const unsigned short* wk = wfB + (size_t)k * 16384 + (size_t)(2 * wave) * 4096;
        short8 bva[8], bvb[8];
        #pragma unroll
        for (int t = 0; t < 8; ++t) {
            bva[t] = *(const short8*)(wk + (size_t)t * 512 + (size_t)lane * 8);
            bvb[t] = *(const short8*)(wk + 4096 + (size_t)t * 512 + (size_t)lane * 8);
        }
        // 2. blend (sorted layout, lane-local) + permute-write
        #pragma unroll
        for (int pt = 0; pt < 2; ++pt) {
            float2v A0 = (float2v){wxy[pt][0], wxy[pt][0]};
            float2v A1 = (float2v){wxy[pt][1], wxy[pt][1]};
            float2v B0 = (float2v){wxy[pt][2], wxy[pt][2]};
            float2v B1 = (float2v){wxy[pt][3], wxy[pt][3]};
            #pragma unroll
            for (int qq = 0; qq < 2; ++qq) {
                uint4v res;
                #pragma unroll
                for (int j = 0; j < 4; ++j) {
                    float2v p00 = up2(u[pt][qq * 4 + 0][j]);
                    float2v p01 = up2(u[pt][qq * 4 + 1][j]);
                    float2v p10 = up2(u[pt][qq * 4 + 2][j]);
                    float2v p11 = up2(u[pt][qq * 4 + 3][j]);
                    float2v t0 = __builtin_elementwise_fma(A1, p01, A0 * p00);
                    float2v t1 = __builtin_elementwise_fma(A1, p11, A0 * p10);
                    float2v rr = __builtin_elementwise_fma(B1, t1, B0 * t0);
                    res[j] = packbf2(rr.x, rr.y);
                }
                smw[wbase + (pt * 2 + qq) * 64 + lane] = res;
            }
        }
        // 3. next tap's addresses + gathers (reuse u)
        if (k < 8) {
            CALC_TAP(k + 1);
            LOAD_TAP();
        }
        // 4. permute-read into fragment layout, then MFMAs (shared weights)
        short8 afr[2][2];
        #pragma unroll
        for (int pt = 0; pt < 2; ++pt)
            #pragma unroll
            for (int qq = 0; qq < 2; ++qq)
                afr[pt][qq] = __builtin_bit_cast(short8, smw[rIdx + (pt * 2 + qq) * 64]);
        #pragma unroll
        for (int t = 0; t < 8; ++t) {
            acc[0][t] = __builtin_amdgcn_mfma_f32_16x16x32_bf16(afr[0][0], bva[t], acc[0][t], 0, 0, 0);
            acc[1][t] = __builtin_amdgcn_mfma_f32_16x16x32_bf16(afr[1][0], bva[t], acc[1][t], 0, 0, 0);
        }
        #pragma unroll
        for (int t = 0; t < 8; ++t) {
            acc[0][t] = __builtin_amdgcn_mfma_f32_16x16x32_bf16(afr[0][1], bvb[t], acc[0][t], 0, 0, 0);
            acc[1][t] = __builtin_amdgcn_mfma_f32_16x16x32_bf16(afr[1][1], bvb[t], acc[1][t], 0, 0, 0);
        }
    }
#undef CALC_TAP
#undef LOAD_TAP

    // ================= Phase 3: merge + attention epilogue =====================
    if (wave == 1) {
        #pragma unroll
        for (int pt = 0; pt < 2; ++pt)
            #pragma unroll
            for (int t = 0; t < 8; ++t)
                red[(pt * 8 + t) * 64 + lane] = acc[pt][t];
    }
    __syncthreads();
    if (wave == 0) {
        #pragma unroll
        for (int pt = 0; pt < 2; ++pt)
            #pragma unroll
            for (int t = 0; t < 8; ++t)
                acc[pt][t] += red[(pt * 8 + t) * 64 + lane];

        float wA[8];
        #pragma unroll
        for (int t = 0; t < 8; ++t) wA[t] = w_attn[16 * t + col];
        float battn = b_attn[0];
        #pragma unroll
        for (int pt = 0; pt < 2; ++pt) {
            float sig[4];
            #pragma unroll
            for (int r = 0; r < 4; ++r) {
                float pr = 0.0f;
                #pragma unroll
                for (int t = 0; t < 8; ++t) pr = fmaf(acc[pt][t][r], wA[t], pr);
                #pragma unroll
                for (int m = 1; m < 16; m <<= 1) pr += __shfl_xor(pr, m, 64);
                sig[r] = 1.0f / (1.0f + expf(-(pr + battn)));
            }
            #pragma unroll
            for (int t = 0; t < 8; ++t) {
                int o = 16 * t + col;
                float4v v;
                #pragma unroll
                for (int r = 0; r < 4; ++r)
                    v[r] = fmaxf(acc[pt][t][r] * sig[r], 0.0f);
                float* dst = out + ((size_t)(b * Cch + o)) * HW + h * Ww + w0 + 16 * pt + 4 * s;
                *(float4v*)dst = v;
            }
        }
    }
}

// ---- launch ------------------------------------------------------------------
extern "C" void kernel_launch(void* const* d_in, const int* in_sizes, int n_in,
                              void* d_out, int out_size, void* d_ws, size_t ws_size,
                              hipStream_t stream) {
    const float* x      = (const float*)d_in[0];
    const float* w_off  = (const float*)d_in[1];
    const float* b_off  = (const float*)d_in[2];
    const float* w_def  = (const float*)d_in[3];
    const float* b_def  = (const float*)d_in[4];
    const float* w_attn = (const float*)d_in[5];
    const float* b_attn = (const float*)d_in[6];
    float* out = (float*)d_out;

    char* ws = (char*)d_ws;
    unsigned short* xt  = (unsigned short*)ws;                       // 16,777,216 B
    unsigned short* wfB = (unsigned short*)(ws + 16777216);          //    294,912 B
    unsigned short* wfO = (unsigned short*)(ws + 17072128);          //     73,728 B

    prep_all<<<1744, 256, 0, stream>>>(x, xt, w_def, w_off, wfB, wfO);
    fused_srt<<<2048, 128, 0, stream>>>(xt, wfB, wfO, b_off, b_def, w_attn, b_attn, out);
}

// Round 19
// 150.772 us; speedup vs baseline: 1.1271x; 1.0090x over previous
//
#include <hip/hip_runtime.h>
#include <math.h>

#define Cch 128
#define Hh 128
#define Ww 128
#define HW (Hh * Ww)

typedef __attribute__((ext_vector_type(8))) short short8;
typedef __attribute__((ext_vector_type(4))) float float4v;
typedef __attribute__((ext_vector_type(2))) float float2v;
typedef __attribute__((ext_vector_type(4))) unsigned int uint4v;

__device__ __forceinline__ unsigned short f2bf(float f) {
    unsigned u = __float_as_uint(f);
    return (unsigned short)((u + 0x8000u) >> 16);
}
__device__ __forceinline__ float2v up2(unsigned u) {
    return (float2v){__uint_as_float(u << 16), __uint_as_float(u & 0xffff0000u)};
}
__device__ __forceinline__ unsigned packbf2(float lo, float hi) {
    unsigned a = __float_as_uint(lo), b = __float_as_uint(hi);
    return ((a + 0x8000u) >> 16) | ((b + 0x8000u) & 0xffff0000u);
}

// ---- K1+K2 merged: blocks [0,1024) pack x -> xt bf16; [1024,1744) build
// weight fragments. Fully independent jobs -> one launch boundary deleted.
#define NFB (9 * 4 * 8 * 64 * 8)
#define NFO (9 * 4 * 2 * 64 * 8)
__global__ __launch_bounds__(256) void prep_all(const float* __restrict__ x,
                                                unsigned short* __restrict__ xt,
                                                const float* __restrict__ w_def,
                                                const float* __restrict__ w_off,
                                                unsigned short* __restrict__ wfB,
                                                unsigned short* __restrict__ wfO) {
    __shared__ unsigned int tile[64][68];   // [px][c2], 17,408 B (pack path only)
    int t   = threadIdx.x;
    int blk = blockIdx.x;
    if (blk < 1024) {
        int b   = blk >> 8;
        int p0  = (blk & 255) << 6;
        const float* xb = x + (size_t)b * Cch * HW + p0;
        int c2i = t >> 4;                  // 0..15 (channel-pair row)
        int q   = t & 15;                  // px quad
        #pragma unroll
        for (int it = 0; it < 4; ++it) {
            int c2 = it * 16 + c2i;
            int px = q * 4;
            float4v a = *(const float4v*)&xb[(size_t)(2 * c2) * HW + px];
            float4v c = *(const float4v*)&xb[(size_t)(2 * c2 + 1) * HW + px];
            #pragma unroll
            for (int j = 0; j < 4; ++j)
                tile[px + j][c2] = packbf2(a[j], c[j]);
        }
        __syncthreads();
        unsigned short* xtb = xt + (size_t)b * HW * Cch + (size_t)p0 * Cch;
        int g  = t & 15;                   // channel octet
        int pw = t >> 4;                   // 0..15
        #pragma unroll
        for (int it = 0; it < 4; ++it) {
            int p = pw + 16 * it;
            uint4v v = *(const uint4v*)&tile[p][g * 4];
            *(uint4v*)(xtb + (size_t)p * Cch + g * 8) = v;
        }
    } else {
        int idx = (blk - 1024) * 256 + t;
        if (idx < NFB) {
            int j = idx & 7, lane = (idx >> 3) & 63, tt = (idx >> 9) & 7;
            int q = (idx >> 12) & 3, k = idx >> 14;
            int c = 32 * q + 8 * (lane >> 4) + j;
            int o = 16 * tt + (lane & 15);
            wfB[idx] = f2bf(w_def[(size_t)(o * Cch + c) * 9 + k]);
        } else if (idx < NFB + NFO) {
            int i2 = idx - NFB;
            int j = i2 & 7, lane = (i2 >> 3) & 63, tt = (i2 >> 9) & 1;
            int q = (i2 >> 10) & 3, k = i2 >> 12;
            int c = 32 * q + 8 * (lane >> 4) + j;
            int o = 16 * tt + (lane & 15);
            wfO[i2] = (o < 18) ? f2bf(w_off[(size_t)(o * Cch + c) * 9 + k]) : (unsigned short)0;
        }
    }
}

// ---- block -> (b, h, w0): XCD-pinned (blk%8 = XCD, 2 XCDs per image) ---------
__device__ __forceinline__ void blk_map(int blk, int& b, int& h, int& w0) {
    int xcd = blk & 7;
    b = xcd >> 1;
    int seg = ((xcd & 1) << 8) | (blk >> 3);  // 0..511
    h  = seg >> 2;
    w0 = (seg & 3) << 5;
}

// ---- K3: ANCHOR config (R9/R17-measured ~70us, byte-exact) -------------------
// Latency-bound fixed point: ~2.5x above the L1/L2 BW floor (~25-29us), with
// all structural escapes measured-negative (R3/R7/R8/R10/R13/R15 ledger; R17
// merge verified safe). Remaining escape (full-asm VMEM loop with hand vmcnt)
// is negative-EV at observed bench reliability. Held as final.
__global__ __launch_bounds__(128, 2) void fused_srt(const unsigned short* __restrict__ xt,
                                                    const unsigned short* __restrict__ wfB,
                                                    const unsigned short* __restrict__ wfO,
                                                    const float* __restrict__ b_off,
                                                    const float* __restrict__ b_def,
                                                    const float* __restrict__ w_attn,
                                                    const float* __restrict__ b_attn,
                                                    float* __restrict__ out) {
    __shared__ float4v red[2 * 8 * 64];   // 16 KiB
    __shared__ float   offs[32 * 18];     // 2.3 KiB
    __shared__ uint4v  smw[2 * 4 * 64];   // 8 KiB: per-wave sorted->frag permute
    int b, h, w0;
    blk_map(blockIdx.x, b, h, w0);
    int tid  = threadIdx.x;
    int wave = tid >> 6;
    int lane = tid & 63;
    int col  = lane & 15;
    int s    = lane >> 4;
    int spx  = lane >> 2;          // sorted: pixel index 0..15
    int sch  = lane & 3;           // sorted: 16-B chunk within 64-B row segment
    int cbase = 64 * wave;
    int csrt  = cbase + sch * 8;   // ushort offset of this lane's chunk
    int wbase = wave * 256;        // smw base (uint4v units)
    int rIdx  = wbase + ((lane & 15) * 4 + (lane >> 4));  // frag-gather source

    const unsigned short* xtb = xt + (size_t)b * HW * Cch;

    // ================= Phase 1: offset conv (sorted loads + permute) ==========
    {
        float4v acc2[2][2];
        #pragma unroll
        for (int pt = 0; pt < 2; ++pt)
            #pragma unroll
            for (int t = 0; t < 2; ++t) {
                int o = 16 * t + col;
                float bv = (wave == 0 && o < 18) ? b_off[o] : 0.0f;
                acc2[pt][t] = (float4v){bv, bv, bv, bv};
            }

        #pragma unroll
        for (int k = 0; k < 9; ++k) {
            int y = h + (k / 3) - 1;
            bool vy = (y >= 0) && (y < Hh);
            int yc = min(max(y, 0), Hh - 1);
            int dxk = (k % 3) - 1;
            int  ofs[2];
            bool val[2];
            #pragma unroll
            for (int pt = 0; pt < 2; ++pt) {
                int px = w0 + 16 * pt + spx;
                int xs = px + dxk;
                val[pt] = vy && (xs >= 0) && (xs < Ww);
                int xc  = min(max(xs, 0), Ww - 1);
                ofs[pt] = (yc * Ww + xc) * Cch + csrt;
            }
            #pragma unroll
            for (int pt = 0; pt < 2; ++pt)
                #pragma unroll
                for (int qq = 0; qq < 2; ++qq) {
                    uint4v av = *(const uint4v*)(xtb + ofs[pt] + 32 * qq);
                    if (!val[pt]) av = (uint4v){0u, 0u, 0u, 0u};
                    smw[wbase + (pt * 2 + qq) * 64 + lane] = av;
                }
            short8 aa[2][2];
            #pragma unroll
            for (int pt = 0; pt < 2; ++pt)
                #pragma unroll
                for (int qq = 0; qq < 2; ++qq)
                    aa[pt][qq] = __builtin_bit_cast(short8, smw[rIdx + (pt * 2 + qq) * 64]);
            #pragma unroll
            for (int qq = 0; qq < 2; ++qq) {
                int q = 2 * wave + qq;
                #pragma unroll
                for (int t = 0; t < 2; ++t) {
                    short8 bv = *(const short8*)(wfO + ((size_t)((k * 4 + q) * 2 + t) * 64 + lane) * 8);
                    #pragma unroll
                    for (int pt = 0; pt < 2; ++pt)
                        acc2[pt][t] = __builtin_amdgcn_mfma_f32_16x16x32_bf16(aa[pt][qq], bv, acc2[pt][t], 0, 0, 0);
                }
            }
        }
        if (wave == 1) {
            #pragma unroll
            for (int pt = 0; pt < 2; ++pt)
                #pragma unroll
                for (int t = 0; t < 2; ++t)
                    red[(pt * 2 + t) * 64 + lane] = acc2[pt][t];
        }
        __syncthreads();
        if (wave == 0) {
            #pragma unroll
            for (int pt = 0; pt < 2; ++pt)
                #pragma unroll
                for (int t = 0; t < 2; ++t) {
                    float4v v = acc2[pt][t] + red[(pt * 2 + t) * 64 + lane];
                    int o = 16 * t + col;
                    if (o < 18) {
                        #pragma unroll
                        for (int r = 0; r < 4; ++r)
                            offs[(16 * pt + 4 * s + r) * 18 + o] = v[r];
                    }
                }
        }
        __syncthreads();
    }

    // ================= Phase 2: sorted gather pipeline + permute + MFMA =======
    float4v acc[2][8];
    #pragma unroll
    for (int pt = 0; pt < 2; ++pt)
        #pragma unroll
        for (int t = 0; t < 8; ++t) {
            float bv = (wave == 0) ? b_def[16 * t + col] : 0.0f;
            acc[pt][t] = (float4v){bv, bv, bv, bv};
        }

    int    oaddr[2][4];   // [pt][corner]
    float  wxy[2][4];     // [pt][a0,a1,b0,b1]
    uint4v u[2][8];       // [pt][qq*4 + corner]

#define CALC_TAP(K_) do {                                                    \
    int ky = ((K_) * 11) >> 5;                                               \
    int kx = (K_) - 3 * ky;                                                  \
    _Pragma("unroll")                                                        \
    for (int pt = 0; pt < 2; ++pt) {                                         \
        int pxl = 16 * pt + spx;                                             \
        int px  = w0 + pxl;                                                  \
        float2 dv = *(const float2*)&offs[pxl * 18 + 2 * (K_)];              \
        float ys = (float)(h - 1 + ky) + dv.x;                               \
        float xs = (float)(px - 1 + kx) + dv.y;                              \
        float y0f = floorf(ys), x0f = floorf(xs);                            \
        float wy = ys - y0f, wx = xs - x0f;                                  \
        int y0 = (int)y0f, x0 = (int)x0f;                                    \
        bool vy0 = (y0 >= 0) && (y0 < Hh);                                   \
        bool vy1 = (y0 + 1 >= 0) && (y0 + 1 < Hh);                           \
        bool vx0 = (x0 >= 0) && (x0 < Ww);                                   \
        bool vx1 = (x0 + 1 >= 0) && (x0 + 1 < Ww);                           \
        int y0c = min(max(y0, 0), Hh - 1), y1c = min(max(y0 + 1, 0), Hh - 1);\
        int x0c = min(max(x0, 0), Ww - 1), x1c = min(max(x0 + 1, 0), Ww - 1);\
        wxy[pt][0] = vx0 ? (1.0f - wx) : 0.0f;                               \
        wxy[pt][1] = vx1 ? wx : 0.0f;                                        \
        wxy[pt][2] = vy0 ? (1.0f - wy) : 0.0f;                               \
        wxy[pt][3] = vy1 ? wy : 0.0f;                                        \
        oaddr[pt][0] = (y0c * Ww + x0c) * Cch + csrt;                        \
        oaddr[pt][1] = (y0c * Ww + x1c) * Cch + csrt;                        \
        oaddr[pt][2] = (y1c * Ww + x0c) * Cch + csrt;                        \
        oaddr[pt][3] = (y1c * Ww + x1c) * Cch + csrt;                        \
    }                                                                        \
} while (0)

#define LOAD_TAP() do {                                                      \
    _Pragma("unroll")                                                        \
    for (int pt = 0; pt < 2; ++pt)                                           \
        _Pragma("unroll")                                                    \
        for (int qq = 0; qq < 2; ++qq)                                       \
            _Pragma("unroll")                                                \
            for (int c4 = 0; c4 < 4; ++c4)                                   \
                u[pt][qq * 4 + c4] =                                         \
                    *(const uint4v*)(xtb + oaddr[pt][c4] + 32 * qq);         \
} while (0)

    CALC_TAP(0);
    LOAD_TAP();

    #pragma unroll
    for (int k = 0; k < 9; ++k) {
        // 1. weight prefetch (both halves at top -- measured-good schedule)
        const unsigned short* wk = wfB + (size_t)k * 16384 + (size_t)(2 * wave) * 4096;
        short8 bva[8], bvb[8];
        #pragma unroll
        for (int t = 0; t < 8; ++t) {
            bva[t] = *(const short8*)(wk + (size_t)t * 512 + (size_t)lane * 8);
            bvb[t] = *(const short8*)(wk + 4096 + (size_t)t * 512 + (size_t)lane * 8);
        }
        // 2. blend (sorted layout, lane-local) + permute-write
        #pragma unroll
        for (int pt = 0; pt < 2; ++pt) {
            float2v A0 = (float2v){wxy[pt][0], wxy[pt][0]};
            float2v A1 = (float2v){wxy[pt][1], wxy[pt][1]};
            float2v B0 = (float2v){wxy[pt][2], wxy[pt][2]};
            float2v B1 = (float2v){wxy[pt][3], wxy[pt][3]};
            #pragma unroll
            for (int qq = 0; qq < 2; ++qq) {
                uint4v res;
                #pragma unroll
                for (int j = 0; j < 4; ++j) {
                    float2v p00 = up2(u[pt][qq * 4 + 0][j]);
                    float2v p01 = up2(u[pt][qq * 4 + 1][j]);
                    float2v p10 = up2(u[pt][qq * 4 + 2][j]);
                    float2v p11 = up2(u[pt][qq * 4 + 3][j]);
                    float2v t0 = __builtin_elementwise_fma(A1, p01, A0 * p00);
                    float2v t1 = __builtin_elementwise_fma(A1, p11, A0 * p10);
                    float2v rr = __builtin_elementwise_fma(B1, t1, B0 * t0);
                    res[j] = packbf2(rr.x, rr.y);
                }
                smw[wbase + (pt * 2 + qq) * 64 + lane] = res;
            }
        }
        // 3. next tap's addresses + gathers (reuse u)
        if (k < 8) {
            CALC_TAP(k + 1);
            LOAD_TAP();
        }
        // 4. permute-read into fragment layout, then MFMAs (shared weights)
        short8 afr[2][2];
        #pragma unroll
        for (int pt = 0; pt < 2; ++pt)
            #pragma unroll
            for (int qq = 0; qq < 2; ++qq)
                afr[pt][qq] = __builtin_bit_cast(short8, smw[rIdx + (pt * 2 + qq) * 64]);
        #pragma unroll
        for (int t = 0; t < 8; ++t) {
            acc[0][t] = __builtin_amdgcn_mfma_f32_16x16x32_bf16(afr[0][0], bva[t], acc[0][t], 0, 0, 0);
            acc[1][t] = __builtin_amdgcn_mfma_f32_16x16x32_bf16(afr[1][0], bva[t], acc[1][t], 0, 0, 0);
        }
        #pragma unroll
        for (int t = 0; t < 8; ++t) {
            acc[0][t] = __builtin_amdgcn_mfma_f32_16x16x32_bf16(afr[0][1], bvb[t], acc[0][t], 0, 0, 0);
            acc[1][t] = __builtin_amdgcn_mfma_f32_16x16x32_bf16(afr[1][1], bvb[t], acc[1][t], 0, 0, 0);
        }
    }
#undef CALC_TAP
#undef LOAD_TAP

    // ================= Phase 3: merge + attention epilogue =====================
    if (wave == 1) {
        #pragma unroll
        for (int pt = 0; pt < 2; ++pt)
            #pragma unroll
            for (int t = 0; t < 8; ++t)
                red[(pt * 8 + t) * 64 + lane] = acc[pt][t];
    }
    __syncthreads();
    if (wave == 0) {
        #pragma unroll
        for (int pt = 0; pt < 2; ++pt)
            #pragma unroll
            for (int t = 0; t < 8; ++t)
                acc[pt][t] += red[(pt * 8 + t) * 64 + lane];

        float wA[8];
        #pragma unroll
        for (int t = 0; t < 8; ++t) wA[t] = w_attn[16 * t + col];
        float battn = b_attn[0];
        #pragma unroll
        for (int pt = 0; pt < 2; ++pt) {
            float sig[4];
            #pragma unroll
            for (int r = 0; r < 4; ++r) {
                float pr = 0.0f;
                #pragma unroll
                for (int t = 0; t < 8; ++t) pr = fmaf(acc[pt][t][r], wA[t], pr);
                #pragma unroll
                for (int m = 1; m < 16; m <<= 1) pr += __shfl_xor(pr, m, 64);
                sig[r] = 1.0f / (1.0f + expf(-(pr + battn)));
            }
            #pragma unroll
            for (int t = 0; t < 8; ++t) {
                int o = 16 * t + col;
                float4v v;
                #pragma unroll
                for (int r = 0; r < 4; ++r)
                    v[r] = fmaxf(acc[pt][t][r] * sig[r], 0.0f);
                float* dst = out + ((size_t)(b * Cch + o)) * HW + h * Ww + w0 + 16 * pt + 4 * s;
                *(float4v*)dst = v;
            }
        }
    }
}

// ---- launch ------------------------------------------------------------------
extern "C" void kernel_launch(void* const* d_in, const int* in_sizes, int n_in,
                              void* d_out, int out_size, void* d_ws, size_t ws_size,
                              hipStream_t stream) {
    const float* x      = (const float*)d_in[0];
    const float* w_off  = (const float*)d_in[1];
    const float* b_off  = (const float*)d_in[2];
    const float* w_def  = (const float*)d_in[3];
    const float* b_def  = (const float*)d_in[4];
    const float* w_attn = (const float*)d_in[5];
    const float* b_attn = (const float*)d_in[6];
    float* out = (float*)d_out;

    char* ws = (char*)d_ws;
    unsigned short* xt  = (unsigned short*)ws;                       // 16,777,216 B
    unsigned short* wfB = (unsigned short*)(ws + 16777216);          //    294,912 B
    unsigned short* wfO = (unsigned short*)(ws + 17072128);          //     73,728 B

    prep_all<<<1744, 256, 0, stream>>>(x, xt, w_def, w_off, wfB, wfO);
    fused_srt<<<2048, 128, 0, stream>>>(xt, wfB, wfO, b_off, b_def, w_attn, b_attn, out);
}

// Round 20
// 150.705 us; speedup vs baseline: 1.1276x; 1.0004x over previous
//
#include <hip/hip_runtime.h>
#include <math.h>

#define Cch 128
#define Hh 128
#define Ww 128
#define HW (Hh * Ww)

typedef __attribute__((ext_vector_type(8))) short short8;
typedef __attribute__((ext_vector_type(4))) float float4v;
typedef __attribute__((ext_vector_type(2))) float float2v;
typedef __attribute__((ext_vector_type(4))) unsigned int uint4v;

__device__ __forceinline__ unsigned short f2bf(float f) {
    unsigned u = __float_as_uint(f);
    return (unsigned short)((u + 0x8000u) >> 16);
}
__device__ __forceinline__ float2v up2(unsigned u) {
    return (float2v){__uint_as_float(u << 16), __uint_as_float(u & 0xffff0000u)};
}
__device__ __forceinline__ unsigned packbf2(float lo, float hi) {
    unsigned a = __float_as_uint(lo), b = __float_as_uint(hi);
    return ((a + 0x8000u) >> 16) | ((b + 0x8000u) & 0xffff0000u);
}

// ---- K1+K2 merged: blocks [0,1024) pack x -> xt bf16; [1024,1744) build
// weight fragments. Fully independent jobs -> one launch boundary deleted.
#define NFB (9 * 4 * 8 * 64 * 8)
#define NFO (9 * 4 * 2 * 64 * 8)
__global__ __launch_bounds__(256) void prep_all(const float* __restrict__ x,
                                                unsigned short* __restrict__ xt,
                                                const float* __restrict__ w_def,
                                                const float* __restrict__ w_off,
                                                unsigned short* __restrict__ wfB,
                                                unsigned short* __restrict__ wfO) {
    __shared__ unsigned int tile[64][68];   // [px][c2], 17,408 B (pack path only)
    int t   = threadIdx.x;
    int blk = blockIdx.x;
    if (blk < 1024) {
        int b   = blk >> 8;
        int p0  = (blk & 255) << 6;
        const float* xb = x + (size_t)b * Cch * HW + p0;
        int c2i = t >> 4;                  // 0..15 (channel-pair row)
        int q   = t & 15;                  // px quad
        #pragma unroll
        for (int it = 0; it < 4; ++it) {
            int c2 = it * 16 + c2i;
            int px = q * 4;
            float4v a = *(const float4v*)&xb[(size_t)(2 * c2) * HW + px];
            float4v c = *(const float4v*)&xb[(size_t)(2 * c2 + 1) * HW + px];
            #pragma unroll
            for (int j = 0; j < 4; ++j)
                tile[px + j][c2] = packbf2(a[j], c[j]);
        }
        __syncthreads();
        unsigned short* xtb = xt + (size_t)b * HW * Cch + (size_t)p0 * Cch;
        int g  = t & 15;                   // channel octet
        int pw = t >> 4;                   // 0..15
        #pragma unroll
        for (int it = 0; it < 4; ++it) {
            int p = pw + 16 * it;
            uint4v v = *(const uint4v*)&tile[p][g * 4];
            *(uint4v*)(xtb + (size_t)p * Cch + g * 8) = v;
        }
    } else {
        int idx = (blk - 1024) * 256 + t;
        if (idx < NFB) {
            int j = idx & 7, lane = (idx >> 3) & 63, tt = (idx >> 9) & 7;
            int q = (idx >> 12) & 3, k = idx >> 14;
            int c = 32 * q + 8 * (lane >> 4) + j;
            int o = 16 * tt + (lane & 15);
            wfB[idx] = f2bf(w_def[(size_t)(o * Cch + c) * 9 + k]);
        } else if (idx < NFB + NFO) {
            int i2 = idx - NFB;
            int j = i2 & 7, lane = (i2 >> 3) & 63, tt = (i2 >> 9) & 1;
            int q = (i2 >> 10) & 3, k = i2 >> 12;
            int c = 32 * q + 8 * (lane >> 4) + j;
            int o = 16 * tt + (lane & 15);
            wfO[i2] = (o < 18) ? f2bf(w_off[(size_t)(o * Cch + c) * 9 + k]) : (unsigned short)0;
        }
    }
}

// ---- block -> (b, h, w0): XCD-pinned (blk%8 = XCD, 2 XCDs per image) ---------
__device__ __forceinline__ void blk_map(int blk, int& b, int& h, int& w0) {
    int xcd = blk & 7;
    b = xcd >> 1;
    int seg = ((xcd & 1) << 8) | (blk >> 3);  // 0..511
    h  = seg >> 2;
    w0 = (seg & 3) << 5;
}

// ---- K3: ANCHOR config (R9/R17/R19-measured ~70us, byte-exact) ---------------
// Latency-bound fixed point: ~2.5x above the L1/L2 BW floor (~25-29us), with
// all structural escapes measured-negative (R3/R7/R8/R10/R13/R15 ledger; R17/
// R19 merge verified safe, thrice-reproduced). Held as final.
__global__ __launch_bounds__(128, 2) void fused_srt(const unsigned short* __restrict__ xt,
                                                    const unsigned short* __restrict__ wfB,
                                                    const unsigned short* __restrict__ wfO,
                                                    const float* __restrict__ b_off,
                                                    const float* __restrict__ b_def,
                                                    const float* __restrict__ w_attn,
                                                    const float* __restrict__ b_attn,
                                                    float* __restrict__ out) {
    __shared__ float4v red[2 * 8 * 64];   // 16 KiB
    __shared__ float   offs[32 * 18];     // 2.3 KiB
    __shared__ uint4v  smw[2 * 4 * 64];   // 8 KiB: per-wave sorted->frag permute
    int b, h, w0;
    blk_map(blockIdx.x, b, h, w0);
    int tid  = threadIdx.x;
    int wave = tid >> 6;
    int lane = tid & 63;
    int col  = lane & 15;
    int s    = lane >> 4;
    int spx  = lane >> 2;          // sorted: pixel index 0..15
    int sch  = lane & 3;           // sorted: 16-B chunk within 64-B row segment
    int cbase = 64 * wave;
    int csrt  = cbase + sch * 8;   // ushort offset of this lane's chunk
    int wbase = wave * 256;        // smw base (uint4v units)
    int rIdx  = wbase + ((lane & 15) * 4 + (lane >> 4));  // frag-gather source

    const unsigned short* xtb = xt + (size_t)b * HW * Cch;

    // ================= Phase 1: offset conv (sorted loads + permute) ==========
    {
        float4v acc2[2][2];
        #pragma unroll
        for (int pt = 0; pt < 2; ++pt)
            #pragma unroll
            for (int t = 0; t < 2; ++t) {
                int o = 16 * t + col;
                float bv = (wave == 0 && o < 18) ? b_off[o] : 0.0f;
                acc2[pt][t] = (float4v){bv, bv, bv, bv};
            }

        #pragma unroll
        for (int k = 0; k < 9; ++k) {
            int y = h + (k / 3) - 1;
            bool vy = (y >= 0) && (y < Hh);
            int yc = min(max(y, 0), Hh - 1);
            int dxk = (k % 3) - 1;
            int  ofs[2];
            bool val[2];
            #pragma unroll
            for (int pt = 0; pt < 2; ++pt) {
                int px = w0 + 16 * pt + spx;
                int xs = px + dxk;
                val[pt] = vy && (xs >= 0) && (xs < Ww);
                int xc  = min(max(xs, 0), Ww - 1);
                ofs[pt] = (yc * Ww + xc) * Cch + csrt;
            }
            #pragma unroll
            for (int pt = 0; pt < 2; ++pt)
                #pragma unroll
                for (int qq = 0; qq < 2; ++qq) {
                    uint4v av = *(const uint4v*)(xtb + ofs[pt] + 32 * qq);
                    if (!val[pt]) av = (uint4v){0u, 0u, 0u, 0u};
                    smw[wbase + (pt * 2 + qq) * 64 + lane] = av;
                }
            short8 aa[2][2];
            #pragma unroll
            for (int pt = 0; pt < 2; ++pt)
                #pragma unroll
                for (int qq = 0; qq < 2; ++qq)
                    aa[pt][qq] = __builtin_bit_cast(short8, smw[rIdx + (pt * 2 + qq) * 64]);
            #pragma unroll
            for (int qq = 0; qq < 2; ++qq) {
                int q = 2 * wave + qq;
                #pragma unroll
                for (int t = 0; t < 2; ++t) {
                    short8 bv = *(const short8*)(wfO + ((size_t)((k * 4 + q) * 2 + t) * 64 + lane) * 8);
                    #pragma unroll
                    for (int pt = 0; pt < 2; ++pt)
                        acc2[pt][t] = __builtin_amdgcn_mfma_f32_16x16x32_bf16(aa[pt][qq], bv, acc2[pt][t], 0, 0, 0);
                }
            }
        }
        if (wave == 1) {
            #pragma unroll
            for (int pt = 0; pt < 2; ++pt)
                #pragma unroll
                for (int t = 0; t < 2; ++t)
                    red[(pt * 2 + t) * 64 + lane] = acc2[pt][t];
        }
        __syncthreads();
        if (wave == 0) {
            #pragma unroll
            for (int pt = 0; pt < 2; ++pt)
                #pragma unroll
                for (int t = 0; t < 2; ++t) {
                    float4v v = acc2[pt][t] + red[(pt * 2 + t) * 64 + lane];
                    int o = 16 * t + col;
                    if (o < 18) {
                        #pragma unroll
                        for (int r = 0; r < 4; ++r)
                            offs[(16 * pt + 4 * s + r) * 18 + o] = v[r];
                    }
                }
        }
        __syncthreads();
    }

    // ================= Phase 2: sorted gather pipeline + permute + MFMA =======
    float4v acc[2][8];
    #pragma unroll
    for (int pt = 0; pt < 2; ++pt)
        #pragma unroll
        for (int t = 0; t < 8; ++t) {
            float bv = (wave == 0) ? b_def[16 * t + col] : 0.0f;
            acc[pt][t] = (float4v){bv, bv, bv, bv};
        }

    int    oaddr[2][4];   // [pt][corner]
    float  wxy[2][4];     // [pt][a0,a1,b0,b1]
    uint4v u[2][8];       // [pt][qq*4 + corner]

#define CALC_TAP(K_) do {                                                    \
    int ky = ((K_) * 11) >> 5;                                               \
    int kx = (K_) - 3 * ky;                                                  \
    _Pragma("unroll")                                                        \
    for (int pt = 0; pt < 2; ++pt) {                                         \
        int pxl = 16 * pt + spx;                                             \
        int px  = w0 + pxl;                                                  \
        float2 dv = *(const float2*)&offs[pxl * 18 + 2 * (K_)];              \
        float ys = (float)(h - 1 + ky) + dv.x;                               \
        float xs = (float)(px - 1 + kx) + dv.y;                              \
        float y0f = floorf(ys), x0f = floorf(xs);                            \
        float wy = ys - y0f, wx = xs - x0f;                                  \
        int y0 = (int)y0f, x0 = (int)x0f;                                    \
        bool vy0 = (y0 >= 0) && (y0 < Hh);                                   \
        bool vy1 = (y0 + 1 >= 0) && (y0 + 1 < Hh);                           \
        bool vx0 = (x0 >= 0) && (x0 < Ww);                                   \
        bool vx1 = (x0 + 1 >= 0) && (x0 + 1 < Ww);                           \
        int y0c = min(max(y0, 0), Hh - 1), y1c = min(max(y0 + 1, 0), Hh - 1);\
        int x0c = min(max(x0, 0), Ww - 1), x1c = min(max(x0 + 1, 0), Ww - 1);\
        wxy[pt][0] = vx0 ? (1.0f - wx) : 0.0f;                               \
        wxy[pt][1] = vx1 ? wx : 0.0f;                                        \
        wxy[pt][2] = vy0 ? (1.0f - wy) : 0.0f;                               \
        wxy[pt][3] = vy1 ? wy : 0.0f;                                        \
        oaddr[pt][0] = (y0c * Ww + x0c) * Cch + csrt;                        \
        oaddr[pt][1] = (y0c * Ww + x1c) * Cch + csrt;                        \
        oaddr[pt][2] = (y1c * Ww + x0c) * Cch + csrt;                        \
        oaddr[pt][3] = (y1c * Ww + x1c) * Cch + csrt;                        \
    }                                                                        \
} while (0)

#define LOAD_TAP() do {                                                      \
    _Pragma("unroll")                                                        \
    for (int pt = 0; pt < 2; ++pt)                                           \
        _Pragma("unroll")                                                    \
        for (int qq = 0; qq < 2; ++qq)                                       \
            _Pragma("unroll")                                                \
            for (int c4 = 0; c4 < 4; ++c4)                                   \
                u[pt][qq * 4 + c4] =                                         \
                    *(const uint4v*)(xtb + oaddr[pt][c4] + 32 * qq);         \
} while (0)

    CALC_TAP(0);
    LOAD_TAP();

    #pragma unroll
    for (int k = 0; k < 9; ++k) {
        // 1. weight prefetch (both halves at top -- measured-good schedule)
        const unsigned short* wk = wfB + (size_t)k * 16384 + (size_t)(2 * wave) * 4096;
        short8 bva[8], bvb[8];
        #pragma unroll
        for (int t = 0; t < 8; ++t) {
            bva[t] = *(const short8*)(wk + (size_t)t * 512 + (size_t)lane * 8);
            bvb[t] = *(const short8*)(wk + 4096 + (size_t)t * 512 + (size_t)lane * 8);
        }
        // 2. blend (sorted layout, lane-local) + permute-write
        #pragma unroll
        for (int pt = 0; pt < 2; ++pt) {
            float2v A0 = (float2v){wxy[pt][0], wxy[pt][0]};
            float2v A1 = (float2v){wxy[pt][1], wxy[pt][1]};
            float2v B0 = (float2v){wxy[pt][2], wxy[pt][2]};
            float2v B1 = (float2v){wxy[pt][3], wxy[pt][3]};
            #pragma unroll
            for (int qq = 0; qq < 2; ++qq) {
                uint4v res;
                #pragma unroll
                for (int j = 0; j < 4; ++j) {
                    float2v p00 = up2(u[pt][qq * 4 + 0][j]);
                    float2v p01 = up2(u[pt][qq * 4 + 1][j]);
                    float2v p10 = up2(u[pt][qq * 4 + 2][j]);
                    float2v p11 = up2(u[pt][qq * 4 + 3][j]);
                    float2v t0 = __builtin_elementwise_fma(A1, p01, A0 * p00);
                    float2v t1 = __builtin_elementwise_fma(A1, p11, A0 * p10);
                    float2v rr = __builtin_elementwise_fma(B1, t1, B0 * t0);
                    res[j] = packbf2(rr.x, rr.y);
                }
                smw[wbase + (pt * 2 + qq) * 64 + lane] = res;
            }
        }
        // 3. next tap's addresses + gathers (reuse u)
        if (k < 8) {
            CALC_TAP(k + 1);
            LOAD_TAP();
        }
        // 4. permute-read into fragment layout, then MFMAs (shared weights)
        short8 afr[2][2];
        #pragma unroll
        for (int pt = 0; pt < 2; ++pt)
            #pragma unroll
            for (int qq = 0; qq < 2; ++qq)
                afr[pt][qq] = __builtin_bit_cast(short8, smw[rIdx + (pt * 2 + qq) * 64]);
        #pragma unroll
        for (int t = 0; t < 8; ++t) {
            acc[0][t] = __builtin_amdgcn_mfma_f32_16x16x32_bf16(afr[0][0], bva[t], acc[0][t], 0, 0, 0);
            acc[1][t] = __builtin_amdgcn_mfma_f32_16x16x32_bf16(afr[1][0], bva[t], acc[1][t], 0, 0, 0);
        }
        #pragma unroll
        for (int t = 0; t < 8; ++t) {
            acc[0][t] = __builtin_amdgcn_mfma_f32_16x16x32_bf16(afr[0][1], bvb[t], acc[0][t], 0, 0, 0);
            acc[1][t] = __builtin_amdgcn_mfma_f32_16x16x32_bf16(afr[1][1], bvb[t], acc[1][t], 0, 0, 0);
        }
    }
#undef CALC_TAP
#undef LOAD_TAP

    // ================= Phase 3: merge + attention epilogue =====================
    if (wave == 1) {
        #pragma unroll
        for (int pt = 0; pt < 2; ++pt)
            #pragma unroll
            for (int t = 0; t < 8; ++t)
                red[(pt * 8 + t) * 64 + lane] = acc[pt][t];
    }
    __syncthreads();
    if (wave == 0) {
        #pragma unroll
        for (int pt = 0; pt < 2; ++pt)
            #pragma unroll
            for (int t = 0; t < 8; ++t)
                acc[pt][t] += red[(pt * 8 + t) * 64 + lane];

        float wA[8];
        #pragma unroll
        for (int t = 0; t < 8; ++t) wA[t] = w_attn[16 * t + col];
        float battn = b_attn[0];
        #pragma unroll
        for (int pt = 0; pt < 2; ++pt) {
            float sig[4];
            #pragma unroll
            for (int r = 0; r < 4; ++r) {
                float pr = 0.0f;
                #pragma unroll
                for (int t = 0; t < 8; ++t) pr = fmaf(acc[pt][t][r], wA[t], pr);
                #pragma unroll
                for (int m = 1; m < 16; m <<= 1) pr += __shfl_xor(pr, m, 64);
                sig[r] = 1.0f / (1.0f + expf(-(pr + battn)));
            }
            #pragma unroll
            for (int t = 0; t < 8; ++t) {
                int o = 16 * t + col;
                float4v v;
                #pragma unroll
                for (int r = 0; r < 4; ++r)
                    v[r] = fmaxf(acc[pt][t][r] * sig[r], 0.0f);
                float* dst = out + ((size_t)(b * Cch + o)) * HW + h * Ww + w0 + 16 * pt + 4 * s;
                *(float4v*)dst = v;
            }
        }
    }
}

// ---- launch ------------------------------------------------------------------
extern "C" void kernel_launch(void* const* d_in, const int* in_sizes, int n_in,
                              void* d_out, int out_size, void* d_ws, size_t ws_size,
                              hipStream_t stream) {
    const float* x      = (const float*)d_in[0];
    const float* w_off  = (const float*)d_in[1];
    const float* b_off  = (const float*)d_in[2];
    const float* w_def  = (const float*)d_in[3];
    const float* b_def  = (const float*)d_in[4];
    const float* w_attn = (const float*)d_in[5];
    const float* b_attn = (const float*)d_in[6];
    float* out = (float*)d_out;

    char* ws = (char*)d_ws;
    unsigned short* xt  = (unsigned short*)ws;                       // 16,777,216 B
    unsigned short* wfB = (unsigned short*)(ws + 16777216);          //    294,912 B
    unsigned short* wfO = (unsigned short*)(ws + 17072128);          //     73,728 B

    prep_all<<<1744, 256, 0, stream>>>(x, xt, w_def, w_off, wfB, wfO);
    fused_srt<<<2048, 128, 0, stream>>>(xt, wfB, wfO, b_off, b_def, w_attn, b_attn, out);
}